// Round 15
// baseline (402.439 us; speedup 1.0000x reference)
//
#include <hip/hip_runtime.h>
#include <hip/hip_bf16.h>

// Problem dims (fixed)
#define B_SZ 2
#define L_SEQ 512
#define D_MODEL 256
#define D_STATE 128
#define D_CONV 4
#define D_INNER 1024
#define DT_RANK 16
#define N_HEADS 8
#define DK 32
#define D_FF 1024
#define R_TOT (B_SZ * L_SEQ)   // 1024 rows
#define DBL_LD (DT_RANK + 2 * D_STATE)  // 272
#define NSEG 16
#define SEGL 32   // L_SEQ / NSEG

typedef __hip_bfloat16 bf16;
typedef __attribute__((ext_vector_type(8))) short short8;   // 8 bf16 = 4 VGPR
typedef __attribute__((ext_vector_type(4))) float floatx4;

// Fast transcendentals (native v_exp/v_log/v_rcp; 1-4 ULP, self-damping in scan)
__device__ inline float fexp(float x) { return __expf(x); }
__device__ inline float frcp(float x) { return __builtin_amdgcn_rcpf(x); }
__device__ inline float silu_f(float x) { return x * frcp(1.f + fexp(-x)); }
__device__ inline float softplus_f(float x) { return (x > 20.f) ? x : __logf(1.f + fexp(x)); }

// 64-lane sum via DPP (VALU pipe, no DS traffic). Result valid in lane 63.
__device__ inline float dpp_sum64(float x) {
    x += __int_as_float(__builtin_amdgcn_update_dpp(0, __float_as_int(x), 0x111, 0xf, 0xf, true));
    x += __int_as_float(__builtin_amdgcn_update_dpp(0, __float_as_int(x), 0x112, 0xf, 0xf, true));
    x += __int_as_float(__builtin_amdgcn_update_dpp(0, __float_as_int(x), 0x114, 0xf, 0xf, true));
    x += __int_as_float(__builtin_amdgcn_update_dpp(0, __float_as_int(x), 0x118, 0xf, 0xf, true));
    x += __int_as_float(__builtin_amdgcn_update_dpp(0, __float_as_int(x), 0x142, 0xf, 0xf, true));
    x += __int_as_float(__builtin_amdgcn_update_dpp(0, __float_as_int(x), 0x143, 0xf, 0xf, true));
    return x;
}

// ---------------------------------------------------------------------------
// Dispatch 0: pack (mem + 9 weights f32->bf16) + LN1 + zero-fill of all
// atomically-accumulated buffers (h1,qb,kb,vb contiguous 4 MB; out 1 MB).
// ---------------------------------------------------------------------------
#define S_MEM 262144
#define S_INW 524288
#define S_XPW 278528
#define S_OPW 262144
#define S_WQ  65536
#define S_WK  65536
#define S_WV  65536
#define S_WO  65536
#define S_W1  262144
#define S_W2  262144
#define S_TOT (S_MEM+S_INW+S_XPW+S_OPW+S_WQ+S_WK+S_WV+S_WO+S_W1+S_W2)
#define PACK_BLKS ((S_TOT + 255) / 256)
#define Z1_F4 (4 * R_TOT * D_MODEL / 4)   // h1+qb+kb+vb float4 count (262144)
#define Z2_F4 (R_TOT * D_MODEL / 4)       // out float4 count (65536)
#define ZERO_BLKS ((Z1_F4 + Z2_F4) / 256) // 1280

__global__ __launch_bounds__(256) void pack_ln1(
    const float* __restrict__ s0, const float* __restrict__ s1,
    const float* __restrict__ s2, const float* __restrict__ s3,
    const float* __restrict__ s4, const float* __restrict__ s5,
    const float* __restrict__ s6, const float* __restrict__ s7,
    const float* __restrict__ s8, const float* __restrict__ s9,
    bf16* __restrict__ dst,
    const float* __restrict__ X, const float* __restrict__ a,
    const float* __restrict__ bvec, bf16* __restrict__ ln1b,
    float* __restrict__ zero1, float* __restrict__ zero2)
{
    __shared__ float r1[256], r2[256];
    if (blockIdx.x < PACK_BLKS) {
        const long i = (long)blockIdx.x * 256 + threadIdx.x;
        if (i >= S_TOT) return;
        const long off[11] = {0, S_MEM, S_MEM+S_INW, S_MEM+S_INW+S_XPW,
            S_MEM+S_INW+S_XPW+S_OPW, S_MEM+S_INW+S_XPW+S_OPW+S_WQ,
            S_MEM+S_INW+S_XPW+S_OPW+S_WQ+S_WK,
            S_MEM+S_INW+S_XPW+S_OPW+S_WQ+S_WK+S_WV,
            S_MEM+S_INW+S_XPW+S_OPW+S_WQ+S_WK+S_WV+S_WO,
            S_MEM+S_INW+S_XPW+S_OPW+S_WQ+S_WK+S_WV+S_WO+S_W1, S_TOT};
        const float* srcs[10] = {s0,s1,s2,s3,s4,s5,s6,s7,s8,s9};
        int seg = 0;
#pragma unroll
        for (int k = 1; k < 10; ++k) if (i >= off[k]) seg = k;
        dst[i] = __float2bfloat16(srcs[seg][i - off[seg]]);
    } else if (blockIdx.x < PACK_BLKS + R_TOT) {
        const int row = blockIdx.x - PACK_BLKS;
        const int t = threadIdx.x;
        const float v = X[(long)row * D_MODEL + t];
        r1[t] = v;
        r2[t] = v * v;
        __syncthreads();
        for (int s = 128; s > 0; s >>= 1) {
            if (t < s) { r1[t] += r1[t + s]; r2[t] += r2[t + s]; }
            __syncthreads();
        }
        const float mean = r1[0] * (1.f / 256.f);
        const float var = (r2[0] - 256.f * mean * mean) * (1.f / 255.f);
        const float sd = sqrtf(fmaxf(var, 0.f));
        const float o = a[t] * (v - mean) / (sd + 1e-6f) + bvec[t];
        ln1b[(long)row * D_MODEL + t] = __float2bfloat16(o);
    } else {
        const long i4 = (long)(blockIdx.x - PACK_BLKS - R_TOT) * 256 + threadIdx.x;
        const float4 z = {0.f, 0.f, 0.f, 0.f};
        if (i4 < Z1_F4)             *(float4*)&zero1[i4 * 4] = z;
        else if (i4 < Z1_F4 + Z2_F4) *(float4*)&zero2[(i4 - Z1_F4) * 4] = z;
    }
}

// ---------------------------------------------------------------------------
// MFMA GEMM: C = epi(A @ W^T + bias)(+res), bf16 inputs, f32/bf16 out.
// ---------------------------------------------------------------------------
template <int EPI>
__global__ __launch_bounds__(256) void mfma_gemm(
    const bf16* __restrict__ A, const bf16* __restrict__ W, int K,
    float* __restrict__ C, bf16* __restrict__ Cb, int ldc,
    const float* __restrict__ bias, const float* __restrict__ res,
    int M, int N)
{
    const int wave = threadIdx.x >> 6;
    const int lane = threadIdx.x & 63;
    const int row16 = lane & 15;
    const int quad  = lane >> 4;
    const int bm = blockIdx.y * 64 + wave * 16;
    const int bn = blockIdx.x * 64;

    floatx4 acc[4];
#pragma unroll
    for (int t = 0; t < 4; ++t) acc[t] = (floatx4){0.f, 0.f, 0.f, 0.f};

    const long arow = (long)(bm + row16) * K;
    for (int k0 = 0; k0 < K; k0 += 32) {
        const short8 av = *(const short8*)(A + arow + k0 + quad * 8);
#pragma unroll
        for (int t = 0; t < 4; ++t) {
            const int gn = bn + t * 16 + row16;
            short8 bv = {0,0,0,0,0,0,0,0};
            if (gn < N) bv = *(const short8*)(W + (long)gn * K + k0 + quad * 8);
            acc[t] = __builtin_amdgcn_mfma_f32_16x16x32_bf16(av, bv, acc[t], 0, 0, 0);
        }
    }

#pragma unroll
    for (int t = 0; t < 4; ++t) {
        const int gn = bn + t * 16 + row16;
        if (gn >= N) continue;
        const float bs = bias ? bias[gn] : 0.f;
#pragma unroll
        for (int r = 0; r < 4; ++r) {
            const int gm = bm + quad * 4 + r;
            float v = acc[t][r] + bs;
            if (EPI == 1) v = fmaxf(v, 0.f);
            const long ci = (long)gm * ldc + gn;
            if (res) v += res[ci];
            if (C)  C[ci] = v;
            if (Cb) Cb[ci] = __float2bfloat16(v);
        }
    }
}

// ---------------------------------------------------------------------------
// Split-K MFMA GEMM: grid (N/64, M/64, SK). atomicAdd into pre-zeroed f32 C.
// kz==0 folds bias and residual.
// ---------------------------------------------------------------------------
template <int SK>
__global__ __launch_bounds__(256) void splitk_gemm(
    const bf16* __restrict__ A, const bf16* __restrict__ W, int K,
    float* __restrict__ C, int ldc,
    const float* __restrict__ bias, const float* __restrict__ res,
    int M, int N)
{
    const int wave = threadIdx.x >> 6;
    const int lane = threadIdx.x & 63;
    const int row16 = lane & 15;
    const int quad  = lane >> 4;
    const int bm = blockIdx.y * 64 + wave * 16;
    const int bn = blockIdx.x * 64;
    const int kz = blockIdx.z;
    const int ksl = K / SK;
    const int kbeg = kz * ksl;

    floatx4 acc[4];
#pragma unroll
    for (int t = 0; t < 4; ++t) acc[t] = (floatx4){0.f, 0.f, 0.f, 0.f};

    const long arow = (long)(bm + row16) * K;
    for (int k0 = kbeg; k0 < kbeg + ksl; k0 += 32) {
        const short8 av = *(const short8*)(A + arow + k0 + quad * 8);
#pragma unroll
        for (int t = 0; t < 4; ++t) {
            const int gn = bn + t * 16 + row16;
            const short8 bv = *(const short8*)(W + (long)gn * K + k0 + quad * 8);
            acc[t] = __builtin_amdgcn_mfma_f32_16x16x32_bf16(av, bv, acc[t], 0, 0, 0);
        }
    }

#pragma unroll
    for (int t = 0; t < 4; ++t) {
        const int gn = bn + t * 16 + row16;
        const float bs = (kz == 0 && bias) ? bias[gn] : 0.f;
#pragma unroll
        for (int r = 0; r < 4; ++r) {
            const int gm = bm + quad * 4 + r;
            float v = acc[t][r] + bs;
            const long ci = (long)gm * ldc + gn;
            if (kz == 0 && res) v += res[ci];
            atomicAdd(&C[ci], v);
        }
    }
}

// ---------------------------------------------------------------------------
// gemm16_ln: block = 16 FULL rows x 256 cols; writes h (f32) + LN(h) (bf16).
// Used for wo (K=256). grid = M/16 blocks.
// ---------------------------------------------------------------------------
__global__ __launch_bounds__(256) void gemm16_ln(
    const bf16* __restrict__ A, const bf16* __restrict__ W, int K,
    const float* __restrict__ bias, const float* __restrict__ res,
    float* __restrict__ Cf,
    const float* __restrict__ lna, const float* __restrict__ lnb,
    bf16* __restrict__ lnout)
{
    __shared__ float tile[16][264];
    __shared__ float red1[16][16];
    __shared__ float red2[16][16];
    const int w = threadIdx.x >> 6;
    const int lane = threadIdx.x & 63;
    const int row16 = lane & 15;
    const int quad  = lane >> 4;
    const int bm = blockIdx.x * 16;

    floatx4 acc[4];
#pragma unroll
    for (int t = 0; t < 4; ++t) acc[t] = (floatx4){0.f, 0.f, 0.f, 0.f};

    const long arow = (long)(bm + row16) * K;
    for (int k0 = 0; k0 < K; k0 += 32) {
        const short8 av = *(const short8*)(A + arow + k0 + quad * 8);
#pragma unroll
        for (int t = 0; t < 4; ++t) {
            const int gn = w * 64 + t * 16 + row16;
            const short8 bv = *(const short8*)(W + (long)gn * K + k0 + quad * 8);
            acc[t] = __builtin_amdgcn_mfma_f32_16x16x32_bf16(av, bv, acc[t], 0, 0, 0);
        }
    }

#pragma unroll
    for (int t = 0; t < 4; ++t) {
        const int gn = w * 64 + t * 16 + row16;
        const float bs = bias ? bias[gn] : 0.f;
#pragma unroll
        for (int r = 0; r < 4; ++r) {
            const int gm = bm + quad * 4 + r;
            float v = acc[t][r] + bs;
            const long ci = (long)gm * D_MODEL + gn;
            if (res) v += res[ci];
            Cf[ci] = v;
            tile[quad * 4 + r][gn] = v;
        }
    }
    __syncthreads();

    const int r = threadIdx.x >> 4;
    const int g = threadIdx.x & 15;
    float s = 0.f, q = 0.f;
#pragma unroll
    for (int i = 0; i < 16; ++i) {
        const float x = tile[r][g * 16 + i];
        s += x; q += x * x;
    }
    red1[r][g] = s; red2[r][g] = q;
    __syncthreads();
    float ts = 0.f, tq = 0.f;
#pragma unroll
    for (int i = 0; i < 16; ++i) { ts += red1[r][i]; tq += red2[r][i]; }
    const float mean = ts * (1.f / 256.f);
    const float var = (tq - 256.f * mean * mean) * (1.f / 255.f);
    const float sd = sqrtf(fmaxf(var, 0.f));
    const long rowbase = (long)(bm + r) * D_MODEL;
#pragma unroll
    for (int i = 0; i < 16; ++i) {
        const int c = g * 16 + i;
        const float o = lna[c] * (tile[r][c] - mean) / (sd + 1e-6f) + lnb[c];
        lnout[rowbase + c] = __float2bfloat16(o);
    }
}

// ---------------------------------------------------------------------------
// LayerNorm -> bf16 (LN2 after split-K out_proj)
// ---------------------------------------------------------------------------
__global__ __launch_bounds__(256) void ln_kernel(
    const float* __restrict__ x, const float* __restrict__ a,
    const float* __restrict__ bvec, bf16* __restrict__ out)
{
    const int row = blockIdx.x;
    const int t = threadIdx.x;
    const float v = x[(long)row * D_MODEL + t];
    __shared__ float r1[256], r2[256];
    r1[t] = v;
    r2[t] = v * v;
    __syncthreads();
    for (int s = 128; s > 0; s >>= 1) {
        if (t < s) { r1[t] += r1[t + s]; r2[t] += r2[t + s]; }
        __syncthreads();
    }
    const float mean = r1[0] * (1.f / 256.f);
    const float var = (r2[0] - 256.f * mean * mean) * (1.f / 255.f);
    const float sd = sqrtf(fmaxf(var, 0.f));
    const float o = a[t] * (v - mean) / (sd + 1e-6f) + bvec[t];
    out[(long)row * D_MODEL + t] = __float2bfloat16(o);
}

// ---------------------------------------------------------------------------
// Merged q/k/v with split-K=2: grid (4, 16, 6). z: which = z>>1, kz = z&1.
// atomicAdd into pre-zeroed q/k/v; bias folded at kz==0.
// ---------------------------------------------------------------------------
__global__ __launch_bounds__(256) void qkv_gemm(
    const bf16* __restrict__ ln2b, const bf16* __restrict__ memb,
    const bf16* __restrict__ WQb, const bf16* __restrict__ WKb,
    const bf16* __restrict__ WVb,
    const float* __restrict__ WQB, const float* __restrict__ WKB,
    const float* __restrict__ WVB,
    float* __restrict__ qb, float* __restrict__ kb, float* __restrict__ vb)
{
    const int which = blockIdx.z >> 1;
    const int kz = blockIdx.z & 1;
    const bf16* A = (which == 0) ? ln2b : memb;
    const bf16* W = (which == 0) ? WQb : (which == 1) ? WKb : WVb;
    const float* bias = (which == 0) ? WQB : (which == 1) ? WKB : WVB;
    float* C = (which == 0) ? qb : (which == 1) ? kb : vb;

    const int wave = threadIdx.x >> 6;
    const int lane = threadIdx.x & 63;
    const int row16 = lane & 15;
    const int quad  = lane >> 4;
    const int bm = blockIdx.y * 64 + wave * 16;
    const int bn = blockIdx.x * 64;
    const int kbeg = kz * (D_MODEL / 2);

    floatx4 acc[4];
#pragma unroll
    for (int t = 0; t < 4; ++t) acc[t] = (floatx4){0.f, 0.f, 0.f, 0.f};

    const long arow = (long)(bm + row16) * D_MODEL;
    for (int k0 = kbeg; k0 < kbeg + D_MODEL / 2; k0 += 32) {
        const short8 av = *(const short8*)(A + arow + k0 + quad * 8);
#pragma unroll
        for (int t = 0; t < 4; ++t) {
            const int gn = bn + t * 16 + row16;
            const short8 bv = *(const short8*)(W + (long)gn * D_MODEL + k0 + quad * 8);
            acc[t] = __builtin_amdgcn_mfma_f32_16x16x32_bf16(av, bv, acc[t], 0, 0, 0);
        }
    }
#pragma unroll
    for (int t = 0; t < 4; ++t) {
        const int gn = bn + t * 16 + row16;
        const float bs = (kz == 0) ? bias[gn] : 0.f;
#pragma unroll
        for (int r = 0; r < 4; ++r) {
            const int gm = bm + quad * 4 + r;
            atomicAdd(&C[(long)gm * D_MODEL + gn], acc[t][r] + bs);
        }
    }
}

// ---------------------------------------------------------------------------
// dt_proj GEMM (K=16) + softplus, writing TRANSPOSED output dtT[b][d][l].
// ---------------------------------------------------------------------------
__global__ __launch_bounds__(256) void dt_gemm_T(
    const float* __restrict__ A /*dbl*/, const float* __restrict__ W /*DTW*/,
    const float* __restrict__ bias, float* __restrict__ dtT)
{
    __shared__ float As[DT_RANK][65];
    __shared__ float Bs[DT_RANK][65];
    __shared__ float Ct[64][65];
    const int bm = blockIdx.y * 64;   // rows (b,l)
    const int bn = blockIdx.x * 64;   // d
    const int tid = threadIdx.x;
    const int tx = tid & 15;
    const int ty = tid >> 4;
    const int r = tid >> 2;
    const int kk = (tid & 3) * 4;
#pragma unroll
    for (int q = 0; q < 4; ++q) {
        As[kk + q][r] = A[(long)(bm + r) * DBL_LD + kk + q];
        Bs[kk + q][r] = W[(long)(bn + r) * DT_RANK + kk + q];
    }
    __syncthreads();
    float acc[4][4] = {};
#pragma unroll
    for (int k = 0; k < DT_RANK; ++k) {
        float a[4], bv[4];
#pragma unroll
        for (int i = 0; i < 4; ++i) a[i] = As[k][ty * 4 + i];
#pragma unroll
        for (int j = 0; j < 4; ++j) bv[j] = Bs[k][tx * 4 + j];
#pragma unroll
        for (int i = 0; i < 4; ++i)
#pragma unroll
            for (int j = 0; j < 4; ++j)
                acc[i][j] = fmaf(a[i], bv[j], acc[i][j]);
    }
#pragma unroll
    for (int i = 0; i < 4; ++i)
#pragma unroll
        for (int j = 0; j < 4; ++j)
            Ct[tx * 4 + j][ty * 4 + i] = softplus_f(acc[i][j] + bias[bn + tx * 4 + j]);
    __syncthreads();
    const int b = bm >> 9;
    const int l0 = bm & 511;
    const int r2 = tid >> 4;
    const int c4 = (tid & 15) * 4;
#pragma unroll
    for (int q = 0; q < 4; ++q) {
        const int dl = r2 + q * 16;
        float4 v = {Ct[dl][c4], Ct[dl][c4 + 1], Ct[dl][c4 + 2], Ct[dl][c4 + 3]};
        *(float4*)&dtT[((long)(b * D_INNER + bn + dl) << 9) + l0 + c4] = v;
    }
}

// ---------------------------------------------------------------------------
// Tiled causal conv(k=4)+SiLU -> ub (bf16 row-major) + uT (f32 [b][d][l]).
// ---------------------------------------------------------------------------
__global__ __launch_bounds__(256) void conv_silu_T(
    const float* __restrict__ xz, const float* __restrict__ cw,
    const float* __restrict__ cb, bf16* __restrict__ ub, float* __restrict__ uT)
{
    __shared__ float t[64][65];
    const int db = blockIdx.x;
    const int lb = blockIdx.y;
    const int b  = blockIdx.z;
    const int tid = threadIdx.x;
    const int r  = tid >> 4;
    const int c4 = (tid & 15) * 4;
    const int d0 = db * 64 + c4;

    const float4 cb4 = *(const float4*)&cb[d0];
    float cwa[4][4];
#pragma unroll
    for (int i = 0; i < 4; ++i) {
        const float4 w = *(const float4*)&cw[(d0 + i) * 4];
        cwa[i][0] = w.x; cwa[i][1] = w.y; cwa[i][2] = w.z; cwa[i][3] = w.w;
    }

#pragma unroll
    for (int q = 0; q < 4; ++q) {
        const int ll = r + q * 16;
        const int l = lb * 64 + ll;
        float s0 = cb4.x, s1 = cb4.y, s2 = cb4.z, s3 = cb4.w;
#pragma unroll
        for (int k = 0; k < D_CONV; ++k) {
            const int ls = l - 3 + k;
            if (ls >= 0) {
                const float4 xv = *(const float4*)&xz[((long)(b * L_SEQ + ls)) * (2 * D_INNER) + d0];
                s0 = fmaf(xv.x, cwa[0][k], s0);
                s1 = fmaf(xv.y, cwa[1][k], s1);
                s2 = fmaf(xv.z, cwa[2][k], s2);
                s3 = fmaf(xv.w, cwa[3][k], s3);
            }
        }
        s0 = silu_f(s0); s1 = silu_f(s1); s2 = silu_f(s2); s3 = silu_f(s3);
        bf16 b0 = __float2bfloat16(s0), b1 = __float2bfloat16(s1);
        bf16 b2 = __float2bfloat16(s2), b3 = __float2bfloat16(s3);
        ushort4 pk;
        pk.x = *reinterpret_cast<unsigned short*>(&b0);
        pk.y = *reinterpret_cast<unsigned short*>(&b1);
        pk.z = *reinterpret_cast<unsigned short*>(&b2);
        pk.w = *reinterpret_cast<unsigned short*>(&b3);
        *reinterpret_cast<ushort4*>(ub + ((long)(b * L_SEQ + l)) * D_INNER + d0) = pk;
        t[c4 + 0][ll] = s0; t[c4 + 1][ll] = s1;
        t[c4 + 2][ll] = s2; t[c4 + 3][ll] = s3;
    }
    __syncthreads();
#pragma unroll
    for (int q = 0; q < 4; ++q) {
        const int dl = r + q * 16;
        float4 v = {t[dl][c4], t[dl][c4 + 1], t[dl][c4 + 2], t[dl][c4 + 3]};
        *(float4*)&uT[((long)(b * D_INNER + db * 64 + dl) << 9) + lb * 64 + c4] = v;
    }
}

// ---------------------------------------------------------------------------
// Fused segmented scan (frozen at its measured plateau ~143 us).
// ---------------------------------------------------------------------------
__global__ __launch_bounds__(1024) void scan_fused(
    const float* __restrict__ dtT, const float* __restrict__ uT,
    const float* __restrict__ dbl, const float* __restrict__ A_log,
    float* __restrict__ ysT)
{
    const int cd = blockIdx.x;            // b*1024 + d
    const int b = cd >> 10;
    const int d = cd & 1023;
    const int w = threadIdx.x >> 6;       // segment 0..15
    const int lane = threadIdx.x & 63;
    const int n0 = lane * 2;

    __shared__ float Sh[NSEG][D_STATE];
    __shared__ float Ph[NSEG][D_STATE];

    const float An0 = -fexp(A_log[(long)d * D_STATE + n0]);
    const float An1 = -fexp(A_log[(long)d * D_STATE + n0 + 1]);

    const float* dtp = dtT + ((long)cd << 9) + w * SEGL;
    const float* up  = uT  + ((long)cd << 9) + w * SEGL;
    const float* blp = dbl + ((long)(b * L_SEQ + w * SEGL)) * DBL_LD + DT_RANK + n0;
    const float* clp = blp + D_STATE;

    if (w < NSEG - 1) {
        float h0 = 0.f, h1 = 0.f, sdt = 0.f;
        for (int s = 0; s < SEGL / 8; ++s) {
            const float4 dt0 = *(const float4*)(dtp + s * 8);
            const float4 dt1 = *(const float4*)(dtp + s * 8 + 4);
            const float4 u0  = *(const float4*)(up + s * 8);
            const float4 u1  = *(const float4*)(up + s * 8 + 4);
            float2 Bv[8];
#pragma unroll
            for (int j = 0; j < 8; ++j)
                Bv[j] = *(const float2*)(blp + (long)(s * 8 + j) * DBL_LD);
            const float dts[8] = {dt0.x, dt0.y, dt0.z, dt0.w, dt1.x, dt1.y, dt1.z, dt1.w};
            const float us[8]  = {u0.x,  u0.y,  u0.z,  u0.w,  u1.x,  u1.y,  u1.z,  u1.w};
#pragma unroll
            for (int j = 0; j < 8; ++j) {
                const float dtv = dts[j];
                sdt += dtv;
                const float dtu = dtv * us[j];
                h0 = fmaf(fexp(dtv * An0), h0, dtu * Bv[j].x);
                h1 = fmaf(fexp(dtv * An1), h1, dtu * Bv[j].y);
            }
        }
        Sh[w][n0] = h0; Sh[w][n0 + 1] = h1;
        Ph[w][n0] = fexp(An0 * sdt); Ph[w][n0 + 1] = fexp(An1 * sdt);
    }
    __syncthreads();

    float h0 = 0.f, h1 = 0.f;
    for (int s = 0; s < w; ++s) {
        h0 = fmaf(Ph[s][n0],     h0, Sh[s][n0]);
        h1 = fmaf(Ph[s][n0 + 1], h1, Sh[s][n0 + 1]);
    }

    float* ysp = ysT + ((long)cd << 9) + w * SEGL;
    for (int s = 0; s < SEGL / 8; ++s) {
        const float4 dt0 = *(const float4*)(dtp + s * 8);
        const float4 dt1 = *(const float4*)(dtp + s * 8 + 4);
        const float4 u0  = *(const float4*)(up + s * 8);
        const float4 u1  = *(const float4*)(up + s * 8 + 4);
        float2 Bv[8], Cv[8];
#pragma unroll
        for (int j = 0; j < 8; ++j) {
            Bv[j] = *(const float2*)(blp + (long)(s * 8 + j) * DBL_LD);
            Cv[j] = *(const float2*)(clp + (long)(s * 8 + j) * DBL_LD);
        }
        const float dts[8] = {dt0.x, dt0.y, dt0.z, dt0.w, dt1.x, dt1.y, dt1.z, dt1.w};
        const float us[8]  = {u0.x,  u0.y,  u0.z,  u0.w,  u1.x,  u1.y,  u1.z,  u1.w};
        float yp[8];
#pragma unroll
        for (int j = 0; j < 8; ++j) {
            const float dtv = dts[j];
            const float dtu = dtv * us[j];
            h0 = fmaf(fexp(dtv * An0), h0, dtu * Bv[j].x);
            h1 = fmaf(fexp(dtv * An1), h1, dtu * Bv[j].y);
            yp[j] = fmaf(h0, Cv[j].x, h1 * Cv[j].y);
        }
#pragma unroll
        for (int j = 0; j < 8; ++j) yp[j] = dpp_sum64(yp[j]);

        if (lane == 63) {
            *(float4*)(ysp + s * 8)     = (float4){yp[0], yp[1], yp[2], yp[3]};
            *(float4*)(ysp + s * 8 + 4) = (float4){yp[4], yp[5], yp[6], yp[7]};
        }
    }
}

// ---------------------------------------------------------------------------
// Fused double-transpose gate: y[row][d] = (ysT + uT*Dp) * silu(z) -> bf16
// ---------------------------------------------------------------------------
__global__ __launch_bounds__(256) void gate_kernel(
    const float* __restrict__ ysT, const float* __restrict__ uT,
    const float* __restrict__ Dp, const float* __restrict__ xz,
    bf16* __restrict__ y)
{
    __shared__ float t[64][65];
    __shared__ float t2[64][65];
    const int db = blockIdx.x;
    const int lb = blockIdx.y;
    const int b  = blockIdx.z;
    const int tid = threadIdx.x;
    const int r  = tid >> 4;
    const int c4 = (tid & 15) * 4;

#pragma unroll
    for (int q = 0; q < 4; ++q) {
        const int dr = r + q * 16;
        const long base = (((long)(b * D_INNER + db * 64 + dr)) << 9) + lb * 64 + c4;
        const float4 v = *(const float4*)&ysT[base];
        const float4 w = *(const float4*)&uT[base];
        t[dr][c4 + 0] = v.x; t[dr][c4 + 1] = v.y;
        t[dr][c4 + 2] = v.z; t[dr][c4 + 3] = v.w;
        t2[dr][c4 + 0] = w.x; t2[dr][c4 + 1] = w.y;
        t2[dr][c4 + 2] = w.z; t2[dr][c4 + 3] = w.w;
    }
    __syncthreads();

    const float4 dp4 = *(const float4*)&Dp[db * 64 + c4];
#pragma unroll
    for (int q = 0; q < 4; ++q) {
        const int lr = r + q * 16;
        const long row = (long)b * L_SEQ + lb * 64 + lr;
        const float4 z4 = *(const float4*)&xz[row * 2 * D_INNER + D_INNER + db * 64 + c4];
        const float r0 = (t[c4 + 0][lr] + t2[c4 + 0][lr] * dp4.x) * silu_f(z4.x);
        const float r1 = (t[c4 + 1][lr] + t2[c4 + 1][lr] * dp4.y) * silu_f(z4.y);
        const float r2 = (t[c4 + 2][lr] + t2[c4 + 2][lr] * dp4.z) * silu_f(z4.z);
        const float r3 = (t[c4 + 3][lr] + t2[c4 + 3][lr] * dp4.w) * silu_f(z4.w);
        bf16 b0 = __float2bfloat16(r0), b1 = __float2bfloat16(r1);
        bf16 b2 = __float2bfloat16(r2), b3 = __float2bfloat16(r3);
        ushort4 pk;
        pk.x = *reinterpret_cast<unsigned short*>(&b0);
        pk.y = *reinterpret_cast<unsigned short*>(&b1);
        pk.z = *reinterpret_cast<unsigned short*>(&b2);
        pk.w = *reinterpret_cast<unsigned short*>(&b3);
        *reinterpret_cast<ushort4*>(y + row * D_INNER + db * 64 + c4) = pk;
    }
}

// ---------------------------------------------------------------------------
// Flash-style cross-attention, QT=16, 16-way k-split -> 512 blocks (2/CU).
// ---------------------------------------------------------------------------
#define QT 16
#define CK 64

__global__ __launch_bounds__(256) void attn_kernel(
    const float* __restrict__ q, const float* __restrict__ k,
    const float* __restrict__ v, bf16* __restrict__ o)
{
    const int qt = blockIdx.x;
    const int hh = blockIdx.y;
    const int b  = blockIdx.z;
    const int t = threadIdx.x;
    const int lane = t & 15;
    const int qa = t >> 4;
    const int q0 = qt * QT + qa;

    __shared__ float Ks[CK][36];
    __shared__ float Vs[CK][36];

    const float scale = 0.17677669529663687f;
    float qr0[32];
    {
        const float* q0p = q + ((long)(b * L_SEQ + q0) * D_MODEL + hh * DK);
#pragma unroll
        for (int i = 0; i < 8; ++i) {
            const float4 a = *(const float4*)&q0p[i * 4];
            qr0[i*4+0] = a.x * scale; qr0[i*4+1] = a.y * scale;
            qr0[i*4+2] = a.z * scale; qr0[i*4+3] = a.w * scale;
        }
    }

    float m0 = -1e30f, l0 = 0.f, o0[32] = {};

    for (int c = 0; c < L_SEQ; c += CK) {
        __syncthreads();
        {
            const int fid = t * 2;
            const int row = fid >> 3;
            const int c0  = (fid & 7) * 4;
            const float* kp = k + ((long)(b * L_SEQ + c + row) * D_MODEL + hh * DK + c0);
            const float* vp = v + ((long)(b * L_SEQ + c + row) * D_MODEL + hh * DK + c0);
            *(float4*)&Ks[row][c0]     = *(const float4*)kp;
            *(float4*)&Ks[row][c0 + 4] = *(const float4*)(kp + 4);
            *(float4*)&Vs[row][c0]     = *(const float4*)vp;
            *(float4*)&Vs[row][c0 + 4] = *(const float4*)(vp + 4);
        }
        __syncthreads();

        float s0[4];
#pragma unroll
        for (int i = 0; i < 4; ++i) {
            const int kk = i * 16 + lane;
            float a0 = 0.f;
#pragma unroll
            for (int dd = 0; dd < 32; dd += 4) {
                const float4 kv = *(const float4*)&Ks[kk][dd];
                a0 = fmaf(qr0[dd+0], kv.x, a0); a0 = fmaf(qr0[dd+1], kv.y, a0);
                a0 = fmaf(qr0[dd+2], kv.z, a0); a0 = fmaf(qr0[dd+3], kv.w, a0);
            }
            s0[i] = a0;
        }

        float cm0 = s0[0];
#pragma unroll
        for (int i = 1; i < 4; ++i) cm0 = fmaxf(cm0, s0[i]);
#pragma unroll
        for (int off = 8; off > 0; off >>= 1)
            cm0 = fmaxf(cm0, __shfl_down(cm0, off, 16));
        cm0 = __shfl(cm0, 0, 16);

        const float nm0 = fmaxf(m0, cm0);
        const float al0 = fexp(m0 - nm0);
        l0 *= al0;
#pragma unroll
        for (int dd = 0; dd < 32; ++dd) o0[dd] *= al0;
        m0 = nm0;

        float p0[4];
#pragma unroll
        for (int i = 0; i < 4; ++i) { p0[i] = fexp(s0[i] - m0); l0 += p0[i]; }

#pragma unroll
        for (int i = 0; i < 4; ++i) {
            const int kk = i * 16 + lane;
#pragma unroll
            for (int dd = 0; dd < 32; dd += 4) {
                const float4 vv = *(const float4*)&Vs[kk][dd];
                o0[dd+0] = fmaf(p0[i], vv.x, o0[dd+0]);
                o0[dd+1] = fmaf(p0[i], vv.y, o0[dd+1]);
                o0[dd+2] = fmaf(p0[i], vv.z, o0[dd+2]);
                o0[dd+3] = fmaf(p0[i], vv.w, o0[dd+3]);
            }
        }
    }

#pragma unroll
    for (int off = 8; off > 0; off >>= 1) {
        l0 += __shfl_down(l0, off, 16);
#pragma unroll
        for (int dd = 0; dd < 32; ++dd) o0[dd] += __shfl_down(o0[dd], off, 16);
    }
    if (lane == 0) {
        const float i0 = 1.f / l0;
        bf16* op0 = o + ((long)(b * L_SEQ + q0) * D_MODEL + hh * DK);
#pragma unroll
        for (int dd = 0; dd < 32; ++dd) op0[dd] = __float2bfloat16(o0[dd] * i0);
    }
}

// ---------------------------------------------------------------------------

extern "C" void kernel_launch(void* const* d_in, const int* in_sizes, int n_in,
                              void* d_out, int out_size, void* d_ws, size_t ws_size,
                              hipStream_t stream) {
    const float* X   = (const float*)d_in[0];
    const float* MEM = (const float*)d_in[1];
    const float* CW  = (const float*)d_in[5];
    const float* CB  = (const float*)d_in[6];
    const float* DTW = (const float*)d_in[8];
    const float* DTB = (const float*)d_in[9];
    const float* ALG = (const float*)d_in[10];
    const float* DP  = (const float*)d_in[11];
    const float* N1A = (const float*)d_in[13];
    const float* N1B = (const float*)d_in[14];
    const float* N2A = (const float*)d_in[15];
    const float* N2B = (const float*)d_in[16];
    const float* N3A = (const float*)d_in[17];
    const float* N3B = (const float*)d_in[18];
    const float* WQB = (const float*)d_in[20];
    const float* WKB = (const float*)d_in[22];
    const float* WVB = (const float*)d_in[24];
    const float* WOB = (const float*)d_in[26];
    const float* W1B = (const float*)d_in[28];
    const float* W2B = (const float*)d_in[30];
    const float* INW = (const float*)d_in[4];
    const float* XPW = (const float*)d_in[7];
    const float* OPW = (const float*)d_in[12];
    const float* WQ  = (const float*)d_in[19];
    const float* WKw = (const float*)d_in[21];
    const float* WVw = (const float*)d_in[23];
    const float* WO  = (const float*)d_in[25];
    const float* W1  = (const float*)d_in[27];
    const float* W2  = (const float*)d_in[29];
    float* out = (float*)d_out;

    // ---- bf16 arena ----
    bf16* bp = (bf16*)d_ws;
    bf16* ub   = bp;  bp += (long)R_TOT * D_INNER;
    bf16* ybb  = bp;  bp += (long)R_TOT * D_INNER;
    bf16* ffab = ybb;
    bf16* ln1b = bp;  bp += (long)R_TOT * D_MODEL;
    bf16* aob  = ln1b;
    bf16* ln2b = bp;  bp += (long)R_TOT * D_MODEL;
    bf16* ln3b = ln2b;
    bf16* arena = bp; bp += S_TOT;
    bf16* MEMb = arena;
    bf16* INWb = MEMb + S_MEM;
    bf16* XPWb = INWb + S_INW;
    bf16* OPWb = XPWb + S_XPW;
    bf16* WQb  = OPWb + S_OPW;
    bf16* WKb  = WQb + S_WQ;
    bf16* WVb  = WKb + S_WK;
    bf16* WOb  = WVb + S_WV;
    bf16* W1b  = WOb + S_WO;
    bf16* W2b  = W1b + S_W1;

    // ---- f32 buffers (h1,qb,kb,vb contiguous for one-shot zeroing) ----
    float* p = (float*)(bp + ((((long)(bp - (bf16*)d_ws)) & 1) ? 1 : 0));
    float* xz  = p;                                  p += (long)R_TOT * 2 * D_INNER;
    float* uT  = p;                                  p += (long)R_TOT * D_INNER;
    float* dbl = p;                                  p += (long)R_TOT * DBL_LD;
    float* dtT = p;                                  p += (long)R_TOT * D_INNER;
    float* ysT = p;                                  p += (long)R_TOT * D_INNER;
    float* h1  = p;                                  p += (long)R_TOT * D_MODEL;
    float* qb  = p;                                  p += (long)R_TOT * D_MODEL;
    float* kb  = p;                                  p += (long)R_TOT * D_MODEL;
    float* vb  = p;                                  p += (long)R_TOT * D_MODEL;
    float* h2  = p;                                  p += (long)R_TOT * D_MODEL;

    const dim3 blk256(256);
    const int MT64 = R_TOT / 64;   // 16

    // 0. pack weights + memory to bf16 + ln1 + zero h1/qb/kb/vb/out
    pack_ln1<<<PACK_BLKS + R_TOT + ZERO_BLKS, blk256, 0, stream>>>(
        MEM, INW, XPW, OPW, WQ, WKw, WVw, WO, W1, W2, arena,
        X, N1A, N1B, ln1b, h1, out);

    // 1. xz = ln1 @ in_proj^T   [R,2048] f32
    mfma_gemm<0><<<dim3(2 * D_INNER / 64, MT64), blk256, 0, stream>>>(
        ln1b, INWb, D_MODEL, xz, nullptr, 2 * D_INNER, nullptr, nullptr,
        R_TOT, 2 * D_INNER);

    // 2. conv+silu -> ub (bf16) + uT (f32 transposed)
    conv_silu_T<<<dim3(D_INNER / 64, L_SEQ / 64, B_SZ), blk256, 0, stream>>>(
        xz, CW, CB, ub, uT);

    // 3. dbl = u @ x_proj^T   [R,272] f32
    mfma_gemm<0><<<dim3((DBL_LD + 63) / 64, MT64), blk256, 0, stream>>>(
        ub, XPWb, D_INNER, dbl, nullptr, DBL_LD, nullptr, nullptr,
        R_TOT, DBL_LD);

    // 4. dt = softplus(dbl[:,:16] @ dt_proj^T + b) -> dtT directly
    dt_gemm_T<<<dim3(D_INNER / 64, MT64), blk256, 0, stream>>>(dbl, DTW, DTB, dtT);

    // 5. fused segmented scan -> ysT
    scan_fused<<<B_SZ * D_INNER, dim3(1024), 0, stream>>>(dtT, uT, dbl, ALG, ysT);

    // 6. gate (double transpose) -> bf16 y[row][d]
    gate_kernel<<<dim3(D_INNER / 64, L_SEQ / 64, B_SZ), blk256, 0, stream>>>(
        ysT, uT, DP, xz, ybb);

    // 7. h1 = x + y @ out_proj^T  (split-K=4, 256 blocks, atomic f32)
    splitk_gemm<4><<<dim3(D_MODEL / 64, MT64, 4), blk256, 0, stream>>>(
        ybb, OPWb, D_INNER, h1, D_MODEL, nullptr, X, R_TOT, D_MODEL);

    // 8. ln2 -> bf16
    ln_kernel<<<R_TOT, blk256, 0, stream>>>(h1, N2A, N2B, ln2b);

    // 9. q,k,v (split-K=2, 384 blocks, atomic f32)
    qkv_gemm<<<dim3(D_MODEL / 64, MT64, 6), blk256, 0, stream>>>(
        ln2b, MEMb, WQb, WKb, WVb, WQB, WKB, WVB, qb, kb, vb);

    // 10. attention -> bf16 (512 blocks)
    attn_kernel<<<dim3(L_SEQ / QT, N_HEADS, B_SZ), blk256, 0, stream>>>(qb, kb, vb, aob);

    // 11. h2 = h1 + ao @ wo^T + wo_b (f32) + fused LN3 -> bf16 (K=256)
    gemm16_ln<<<R_TOT / 16, blk256, 0, stream>>>(
        aob, WOb, D_MODEL, WOB, h1, h2, N3A, N3B, ln3b);

    // 12. ffa = relu(ln3 @ w1^T + b) -> bf16
    mfma_gemm<1><<<dim3(D_FF / 64, MT64), blk256, 0, stream>>>(
        ln3b, W1b, D_MODEL, nullptr, ffab, D_FF, W1B, nullptr, R_TOT, D_FF);

    // 13. out = h2 + ffa @ w2^T + b  (split-K=4, 256 blocks, atomic f32)
    splitk_gemm<4><<<dim3(D_MODEL / 64, MT64, 4), blk256, 0, stream>>>(
        ffab, W2b, D_FF, out, D_MODEL, W2B, h2, R_TOT, D_MODEL);

    (void)in_sizes; (void)n_in; (void)out_size; (void)ws_size;
}

// Round 16
// 381.179 us; speedup vs baseline: 1.0558x; 1.0558x over previous
//
#include <hip/hip_runtime.h>
#include <hip/hip_bf16.h>

// Problem dims (fixed)
#define B_SZ 2
#define L_SEQ 512
#define D_MODEL 256
#define D_STATE 128
#define D_CONV 4
#define D_INNER 1024
#define DT_RANK 16
#define N_HEADS 8
#define DK 32
#define D_FF 1024
#define R_TOT (B_SZ * L_SEQ)   // 1024 rows
#define DBL_LD (DT_RANK + 2 * D_STATE)  // 272
#define NSEG 16
#define SEGL 32   // L_SEQ / NSEG

typedef __hip_bfloat16 bf16;
typedef __attribute__((ext_vector_type(8))) short short8;   // 8 bf16 = 4 VGPR
typedef __attribute__((ext_vector_type(4))) float floatx4;

// Fast transcendentals (native v_exp/v_log/v_rcp; 1-4 ULP, self-damping in scan)
__device__ inline float fexp(float x) { return __expf(x); }
__device__ inline float frcp(float x) { return __builtin_amdgcn_rcpf(x); }
__device__ inline float silu_f(float x) { return x * frcp(1.f + fexp(-x)); }
__device__ inline float softplus_f(float x) { return (x > 20.f) ? x : __logf(1.f + fexp(x)); }

// 64-lane sum via DPP (VALU pipe, no DS traffic). Result valid in lane 63.
__device__ inline float dpp_sum64(float x) {
    x += __int_as_float(__builtin_amdgcn_update_dpp(0, __float_as_int(x), 0x111, 0xf, 0xf, true));
    x += __int_as_float(__builtin_amdgcn_update_dpp(0, __float_as_int(x), 0x112, 0xf, 0xf, true));
    x += __int_as_float(__builtin_amdgcn_update_dpp(0, __float_as_int(x), 0x114, 0xf, 0xf, true));
    x += __int_as_float(__builtin_amdgcn_update_dpp(0, __float_as_int(x), 0x118, 0xf, 0xf, true));
    x += __int_as_float(__builtin_amdgcn_update_dpp(0, __float_as_int(x), 0x142, 0xf, 0xf, true));
    x += __int_as_float(__builtin_amdgcn_update_dpp(0, __float_as_int(x), 0x143, 0xf, 0xf, true));
    return x;
}

// ---------------------------------------------------------------------------
// Dispatch 0: pack (mem + 9 weights f32->bf16) + LN1 + zero-fill of all
// atomically-accumulated buffers (h1,qb,kb,vb 4 MB; out 1 MB; dbl 1.1 MB).
// ---------------------------------------------------------------------------
#define S_MEM 262144
#define S_INW 524288
#define S_XPW 278528
#define S_OPW 262144
#define S_WQ  65536
#define S_WK  65536
#define S_WV  65536
#define S_WO  65536
#define S_W1  262144
#define S_W2  262144
#define S_TOT (S_MEM+S_INW+S_XPW+S_OPW+S_WQ+S_WK+S_WV+S_WO+S_W1+S_W2)
#define PACK_BLKS ((S_TOT + 255) / 256)
#define Z1_F4 (4 * R_TOT * D_MODEL / 4)   // h1+qb+kb+vb float4 count (262144)
#define Z2_F4 (R_TOT * D_MODEL / 4)       // out float4 count (65536)
#define Z3_F4 (R_TOT * DBL_LD / 4)        // dbl float4 count (69632)
#define ZERO_BLKS ((Z1_F4 + Z2_F4 + Z3_F4 + 255) / 256)

__global__ __launch_bounds__(256) void pack_ln1(
    const float* __restrict__ s0, const float* __restrict__ s1,
    const float* __restrict__ s2, const float* __restrict__ s3,
    const float* __restrict__ s4, const float* __restrict__ s5,
    const float* __restrict__ s6, const float* __restrict__ s7,
    const float* __restrict__ s8, const float* __restrict__ s9,
    bf16* __restrict__ dst,
    const float* __restrict__ X, const float* __restrict__ a,
    const float* __restrict__ bvec, bf16* __restrict__ ln1b,
    float* __restrict__ zero1, float* __restrict__ zero2,
    float* __restrict__ zero3)
{
    __shared__ float r1[256], r2[256];
    if (blockIdx.x < PACK_BLKS) {
        const long i = (long)blockIdx.x * 256 + threadIdx.x;
        if (i >= S_TOT) return;
        const long off[11] = {0, S_MEM, S_MEM+S_INW, S_MEM+S_INW+S_XPW,
            S_MEM+S_INW+S_XPW+S_OPW, S_MEM+S_INW+S_XPW+S_OPW+S_WQ,
            S_MEM+S_INW+S_XPW+S_OPW+S_WQ+S_WK,
            S_MEM+S_INW+S_XPW+S_OPW+S_WQ+S_WK+S_WV,
            S_MEM+S_INW+S_XPW+S_OPW+S_WQ+S_WK+S_WV+S_WO,
            S_MEM+S_INW+S_XPW+S_OPW+S_WQ+S_WK+S_WV+S_WO+S_W1, S_TOT};
        const float* srcs[10] = {s0,s1,s2,s3,s4,s5,s6,s7,s8,s9};
        int seg = 0;
#pragma unroll
        for (int k = 1; k < 10; ++k) if (i >= off[k]) seg = k;
        dst[i] = __float2bfloat16(srcs[seg][i - off[seg]]);
    } else if (blockIdx.x < PACK_BLKS + R_TOT) {
        const int row = blockIdx.x - PACK_BLKS;
        const int t = threadIdx.x;
        const float v = X[(long)row * D_MODEL + t];
        r1[t] = v;
        r2[t] = v * v;
        __syncthreads();
        for (int s = 128; s > 0; s >>= 1) {
            if (t < s) { r1[t] += r1[t + s]; r2[t] += r2[t + s]; }
            __syncthreads();
        }
        const float mean = r1[0] * (1.f / 256.f);
        const float var = (r2[0] - 256.f * mean * mean) * (1.f / 255.f);
        const float sd = sqrtf(fmaxf(var, 0.f));
        const float o = a[t] * (v - mean) / (sd + 1e-6f) + bvec[t];
        ln1b[(long)row * D_MODEL + t] = __float2bfloat16(o);
    } else {
        const long i4 = (long)(blockIdx.x - PACK_BLKS - R_TOT) * 256 + threadIdx.x;
        const float4 z = {0.f, 0.f, 0.f, 0.f};
        if (i4 < Z1_F4)                      *(float4*)&zero1[i4 * 4] = z;
        else if (i4 < Z1_F4 + Z2_F4)          *(float4*)&zero2[(i4 - Z1_F4) * 4] = z;
        else if (i4 < Z1_F4 + Z2_F4 + Z3_F4)  *(float4*)&zero3[(i4 - Z1_F4 - Z2_F4) * 4] = z;
    }
}

// ---------------------------------------------------------------------------
// MFMA GEMM: C = epi(A @ W^T + bias)(+res), bf16 inputs, f32/bf16 out.
// ---------------------------------------------------------------------------
template <int EPI>
__global__ __launch_bounds__(256) void mfma_gemm(
    const bf16* __restrict__ A, const bf16* __restrict__ W, int K,
    float* __restrict__ C, bf16* __restrict__ Cb, int ldc,
    const float* __restrict__ bias, const float* __restrict__ res,
    int M, int N)
{
    const int wave = threadIdx.x >> 6;
    const int lane = threadIdx.x & 63;
    const int row16 = lane & 15;
    const int quad  = lane >> 4;
    const int bm = blockIdx.y * 64 + wave * 16;
    const int bn = blockIdx.x * 64;

    floatx4 acc[4];
#pragma unroll
    for (int t = 0; t < 4; ++t) acc[t] = (floatx4){0.f, 0.f, 0.f, 0.f};

    const long arow = (long)(bm + row16) * K;
    for (int k0 = 0; k0 < K; k0 += 32) {
        const short8 av = *(const short8*)(A + arow + k0 + quad * 8);
#pragma unroll
        for (int t = 0; t < 4; ++t) {
            const int gn = bn + t * 16 + row16;
            short8 bv = {0,0,0,0,0,0,0,0};
            if (gn < N) bv = *(const short8*)(W + (long)gn * K + k0 + quad * 8);
            acc[t] = __builtin_amdgcn_mfma_f32_16x16x32_bf16(av, bv, acc[t], 0, 0, 0);
        }
    }

#pragma unroll
    for (int t = 0; t < 4; ++t) {
        const int gn = bn + t * 16 + row16;
        if (gn >= N) continue;
        const float bs = bias ? bias[gn] : 0.f;
#pragma unroll
        for (int r = 0; r < 4; ++r) {
            const int gm = bm + quad * 4 + r;
            float v = acc[t][r] + bs;
            if (EPI == 1) v = fmaxf(v, 0.f);
            const long ci = (long)gm * ldc + gn;
            if (res) v += res[ci];
            if (C)  C[ci] = v;
            if (Cb) Cb[ci] = __float2bfloat16(v);
        }
    }
}

// ---------------------------------------------------------------------------
// Split-K MFMA GEMM: grid (ceil(N/64), M/64, SK). atomicAdd into pre-zeroed
// f32 C. kz==0 folds bias and residual. N-guarded (supports N=272).
// ---------------------------------------------------------------------------
template <int SK>
__global__ __launch_bounds__(256) void splitk_gemm(
    const bf16* __restrict__ A, const bf16* __restrict__ W, int K,
    float* __restrict__ C, int ldc,
    const float* __restrict__ bias, const float* __restrict__ res,
    int M, int N)
{
    const int wave = threadIdx.x >> 6;
    const int lane = threadIdx.x & 63;
    const int row16 = lane & 15;
    const int quad  = lane >> 4;
    const int bm = blockIdx.y * 64 + wave * 16;
    const int bn = blockIdx.x * 64;
    const int kz = blockIdx.z;
    const int ksl = K / SK;
    const int kbeg = kz * ksl;

    floatx4 acc[4];
#pragma unroll
    for (int t = 0; t < 4; ++t) acc[t] = (floatx4){0.f, 0.f, 0.f, 0.f};

    const long arow = (long)(bm + row16) * K;
    for (int k0 = kbeg; k0 < kbeg + ksl; k0 += 32) {
        const short8 av = *(const short8*)(A + arow + k0 + quad * 8);
#pragma unroll
        for (int t = 0; t < 4; ++t) {
            const int gn = bn + t * 16 + row16;
            short8 bv = {0,0,0,0,0,0,0,0};
            if (gn < N) bv = *(const short8*)(W + (long)gn * K + k0 + quad * 8);
            acc[t] = __builtin_amdgcn_mfma_f32_16x16x32_bf16(av, bv, acc[t], 0, 0, 0);
        }
    }

#pragma unroll
    for (int t = 0; t < 4; ++t) {
        const int gn = bn + t * 16 + row16;
        if (gn >= N) continue;
        const float bs = (kz == 0 && bias) ? bias[gn] : 0.f;
#pragma unroll
        for (int r = 0; r < 4; ++r) {
            const int gm = bm + quad * 4 + r;
            float v = acc[t][r] + bs;
            const long ci = (long)gm * ldc + gn;
            if (kz == 0 && res) v += res[ci];
            atomicAdd(&C[ci], v);
        }
    }
}

// ---------------------------------------------------------------------------
// gemm16_ln: block = 16 FULL rows x 256 cols; writes h (f32) + LN(h) (bf16).
// Used for wo (K=256). grid = M/16 blocks.
// ---------------------------------------------------------------------------
__global__ __launch_bounds__(256) void gemm16_ln(
    const bf16* __restrict__ A, const bf16* __restrict__ W, int K,
    const float* __restrict__ bias, const float* __restrict__ res,
    float* __restrict__ Cf,
    const float* __restrict__ lna, const float* __restrict__ lnb,
    bf16* __restrict__ lnout)
{
    __shared__ float tile[16][264];
    __shared__ float red1[16][16];
    __shared__ float red2[16][16];
    const int w = threadIdx.x >> 6;
    const int lane = threadIdx.x & 63;
    const int row16 = lane & 15;
    const int quad  = lane >> 4;
    const int bm = blockIdx.x * 16;

    floatx4 acc[4];
#pragma unroll
    for (int t = 0; t < 4; ++t) acc[t] = (floatx4){0.f, 0.f, 0.f, 0.f};

    const long arow = (long)(bm + row16) * K;
    for (int k0 = 0; k0 < K; k0 += 32) {
        const short8 av = *(const short8*)(A + arow + k0 + quad * 8);
#pragma unroll
        for (int t = 0; t < 4; ++t) {
            const int gn = w * 64 + t * 16 + row16;
            const short8 bv = *(const short8*)(W + (long)gn * K + k0 + quad * 8);
            acc[t] = __builtin_amdgcn_mfma_f32_16x16x32_bf16(av, bv, acc[t], 0, 0, 0);
        }
    }

#pragma unroll
    for (int t = 0; t < 4; ++t) {
        const int gn = w * 64 + t * 16 + row16;
        const float bs = bias ? bias[gn] : 0.f;
#pragma unroll
        for (int r = 0; r < 4; ++r) {
            const int gm = bm + quad * 4 + r;
            float v = acc[t][r] + bs;
            const long ci = (long)gm * D_MODEL + gn;
            if (res) v += res[ci];
            Cf[ci] = v;
            tile[quad * 4 + r][gn] = v;
        }
    }
    __syncthreads();

    const int r = threadIdx.x >> 4;
    const int g = threadIdx.x & 15;
    float s = 0.f, q = 0.f;
#pragma unroll
    for (int i = 0; i < 16; ++i) {
        const float x = tile[r][g * 16 + i];
        s += x; q += x * x;
    }
    red1[r][g] = s; red2[r][g] = q;
    __syncthreads();
    float ts = 0.f, tq = 0.f;
#pragma unroll
    for (int i = 0; i < 16; ++i) { ts += red1[r][i]; tq += red2[r][i]; }
    const float mean = ts * (1.f / 256.f);
    const float var = (tq - 256.f * mean * mean) * (1.f / 255.f);
    const float sd = sqrtf(fmaxf(var, 0.f));
    const long rowbase = (long)(bm + r) * D_MODEL;
#pragma unroll
    for (int i = 0; i < 16; ++i) {
        const int c = g * 16 + i;
        const float o = lna[c] * (tile[r][c] - mean) / (sd + 1e-6f) + lnb[c];
        lnout[rowbase + c] = __float2bfloat16(o);
    }
}

// ---------------------------------------------------------------------------
// LayerNorm -> bf16 (LN2 after split-K out_proj)
// ---------------------------------------------------------------------------
__global__ __launch_bounds__(256) void ln_kernel(
    const float* __restrict__ x, const float* __restrict__ a,
    const float* __restrict__ bvec, bf16* __restrict__ out)
{
    const int row = blockIdx.x;
    const int t = threadIdx.x;
    const float v = x[(long)row * D_MODEL + t];
    __shared__ float r1[256], r2[256];
    r1[t] = v;
    r2[t] = v * v;
    __syncthreads();
    for (int s = 128; s > 0; s >>= 1) {
        if (t < s) { r1[t] += r1[t + s]; r2[t] += r2[t + s]; }
        __syncthreads();
    }
    const float mean = r1[0] * (1.f / 256.f);
    const float var = (r2[0] - 256.f * mean * mean) * (1.f / 255.f);
    const float sd = sqrtf(fmaxf(var, 0.f));
    const float o = a[t] * (v - mean) / (sd + 1e-6f) + bvec[t];
    out[(long)row * D_MODEL + t] = __float2bfloat16(o);
}

// ---------------------------------------------------------------------------
// Merged q/k/v with split-K=2: grid (4, 16, 6). z: which = z>>1, kz = z&1.
// ---------------------------------------------------------------------------
__global__ __launch_bounds__(256) void qkv_gemm(
    const bf16* __restrict__ ln2b, const bf16* __restrict__ memb,
    const bf16* __restrict__ WQb, const bf16* __restrict__ WKb,
    const bf16* __restrict__ WVb,
    const float* __restrict__ WQB, const float* __restrict__ WKB,
    const float* __restrict__ WVB,
    float* __restrict__ qb, float* __restrict__ kb, float* __restrict__ vb)
{
    const int which = blockIdx.z >> 1;
    const int kz = blockIdx.z & 1;
    const bf16* A = (which == 0) ? ln2b : memb;
    const bf16* W = (which == 0) ? WQb : (which == 1) ? WKb : WVb;
    const float* bias = (which == 0) ? WQB : (which == 1) ? WKB : WVB;
    float* C = (which == 0) ? qb : (which == 1) ? kb : vb;

    const int wave = threadIdx.x >> 6;
    const int lane = threadIdx.x & 63;
    const int row16 = lane & 15;
    const int quad  = lane >> 4;
    const int bm = blockIdx.y * 64 + wave * 16;
    const int bn = blockIdx.x * 64;
    const int kbeg = kz * (D_MODEL / 2);

    floatx4 acc[4];
#pragma unroll
    for (int t = 0; t < 4; ++t) acc[t] = (floatx4){0.f, 0.f, 0.f, 0.f};

    const long arow = (long)(bm + row16) * D_MODEL;
    for (int k0 = kbeg; k0 < kbeg + D_MODEL / 2; k0 += 32) {
        const short8 av = *(const short8*)(A + arow + k0 + quad * 8);
#pragma unroll
        for (int t = 0; t < 4; ++t) {
            const int gn = bn + t * 16 + row16;
            const short8 bv = *(const short8*)(W + (long)gn * D_MODEL + k0 + quad * 8);
            acc[t] = __builtin_amdgcn_mfma_f32_16x16x32_bf16(av, bv, acc[t], 0, 0, 0);
        }
    }
#pragma unroll
    for (int t = 0; t < 4; ++t) {
        const int gn = bn + t * 16 + row16;
        const float bs = (kz == 0) ? bias[gn] : 0.f;
#pragma unroll
        for (int r = 0; r < 4; ++r) {
            const int gm = bm + quad * 4 + r;
            atomicAdd(&C[(long)gm * D_MODEL + gn], acc[t][r] + bs);
        }
    }
}

// ---------------------------------------------------------------------------
// dt_proj GEMM (K=16) + softplus, writing TRANSPOSED output dtT[b][d][l].
// ---------------------------------------------------------------------------
__global__ __launch_bounds__(256) void dt_gemm_T(
    const float* __restrict__ A /*dbl*/, const float* __restrict__ W /*DTW*/,
    const float* __restrict__ bias, float* __restrict__ dtT)
{
    __shared__ float As[DT_RANK][65];
    __shared__ float Bs[DT_RANK][65];
    __shared__ float Ct[64][65];
    const int bm = blockIdx.y * 64;   // rows (b,l)
    const int bn = blockIdx.x * 64;   // d
    const int tid = threadIdx.x;
    const int tx = tid & 15;
    const int ty = tid >> 4;
    const int r = tid >> 2;
    const int kk = (tid & 3) * 4;
#pragma unroll
    for (int q = 0; q < 4; ++q) {
        As[kk + q][r] = A[(long)(bm + r) * DBL_LD + kk + q];
        Bs[kk + q][r] = W[(long)(bn + r) * DT_RANK + kk + q];
    }
    __syncthreads();
    float acc[4][4] = {};
#pragma unroll
    for (int k = 0; k < DT_RANK; ++k) {
        float a[4], bv[4];
#pragma unroll
        for (int i = 0; i < 4; ++i) a[i] = As[k][ty * 4 + i];
#pragma unroll
        for (int j = 0; j < 4; ++j) bv[j] = Bs[k][tx * 4 + j];
#pragma unroll
        for (int i = 0; i < 4; ++i)
#pragma unroll
            for (int j = 0; j < 4; ++j)
                acc[i][j] = fmaf(a[i], bv[j], acc[i][j]);
    }
#pragma unroll
    for (int i = 0; i < 4; ++i)
#pragma unroll
        for (int j = 0; j < 4; ++j)
            Ct[tx * 4 + j][ty * 4 + i] = softplus_f(acc[i][j] + bias[bn + tx * 4 + j]);
    __syncthreads();
    const int b = bm >> 9;
    const int l0 = bm & 511;
    const int r2 = tid >> 4;
    const int c4 = (tid & 15) * 4;
#pragma unroll
    for (int q = 0; q < 4; ++q) {
        const int dl = r2 + q * 16;
        float4 v = {Ct[dl][c4], Ct[dl][c4 + 1], Ct[dl][c4 + 2], Ct[dl][c4 + 3]};
        *(float4*)&dtT[((long)(b * D_INNER + bn + dl) << 9) + l0 + c4] = v;
    }
}

// ---------------------------------------------------------------------------
// Tiled causal conv(k=4)+SiLU -> ub (bf16 row-major) + uT (f32 [b][d][l]).
// ---------------------------------------------------------------------------
__global__ __launch_bounds__(256) void conv_silu_T(
    const float* __restrict__ xz, const float* __restrict__ cw,
    const float* __restrict__ cb, bf16* __restrict__ ub, float* __restrict__ uT)
{
    __shared__ float t[64][65];
    const int db = blockIdx.x;
    const int lb = blockIdx.y;
    const int b  = blockIdx.z;
    const int tid = threadIdx.x;
    const int r  = tid >> 4;
    const int c4 = (tid & 15) * 4;
    const int d0 = db * 64 + c4;

    const float4 cb4 = *(const float4*)&cb[d0];
    float cwa[4][4];
#pragma unroll
    for (int i = 0; i < 4; ++i) {
        const float4 w = *(const float4*)&cw[(d0 + i) * 4];
        cwa[i][0] = w.x; cwa[i][1] = w.y; cwa[i][2] = w.z; cwa[i][3] = w.w;
    }

#pragma unroll
    for (int q = 0; q < 4; ++q) {
        const int ll = r + q * 16;
        const int l = lb * 64 + ll;
        float s0 = cb4.x, s1 = cb4.y, s2 = cb4.z, s3 = cb4.w;
#pragma unroll
        for (int k = 0; k < D_CONV; ++k) {
            const int ls = l - 3 + k;
            if (ls >= 0) {
                const float4 xv = *(const float4*)&xz[((long)(b * L_SEQ + ls)) * (2 * D_INNER) + d0];
                s0 = fmaf(xv.x, cwa[0][k], s0);
                s1 = fmaf(xv.y, cwa[1][k], s1);
                s2 = fmaf(xv.z, cwa[2][k], s2);
                s3 = fmaf(xv.w, cwa[3][k], s3);
            }
        }
        s0 = silu_f(s0); s1 = silu_f(s1); s2 = silu_f(s2); s3 = silu_f(s3);
        bf16 b0 = __float2bfloat16(s0), b1 = __float2bfloat16(s1);
        bf16 b2 = __float2bfloat16(s2), b3 = __float2bfloat16(s3);
        ushort4 pk;
        pk.x = *reinterpret_cast<unsigned short*>(&b0);
        pk.y = *reinterpret_cast<unsigned short*>(&b1);
        pk.z = *reinterpret_cast<unsigned short*>(&b2);
        pk.w = *reinterpret_cast<unsigned short*>(&b3);
        *reinterpret_cast<ushort4*>(ub + ((long)(b * L_SEQ + l)) * D_INNER + d0) = pk;
        t[c4 + 0][ll] = s0; t[c4 + 1][ll] = s1;
        t[c4 + 2][ll] = s2; t[c4 + 3][ll] = s3;
    }
    __syncthreads();
#pragma unroll
    for (int q = 0; q < 4; ++q) {
        const int dl = r + q * 16;
        float4 v = {t[dl][c4], t[dl][c4 + 1], t[dl][c4 + 2], t[dl][c4 + 3]};
        *(float4*)&uT[((long)(b * D_INNER + db * 64 + dl) << 9) + lb * 64 + c4] = v;
    }
}

// ---------------------------------------------------------------------------
// Fused segmented scan (frozen at its measured plateau ~140 us).
// ---------------------------------------------------------------------------
__global__ __launch_bounds__(1024) void scan_fused(
    const float* __restrict__ dtT, const float* __restrict__ uT,
    const float* __restrict__ dbl, const float* __restrict__ A_log,
    float* __restrict__ ysT)
{
    const int cd = blockIdx.x;            // b*1024 + d
    const int b = cd >> 10;
    const int d = cd & 1023;
    const int w = threadIdx.x >> 6;       // segment 0..15
    const int lane = threadIdx.x & 63;
    const int n0 = lane * 2;

    __shared__ float Sh[NSEG][D_STATE];
    __shared__ float Ph[NSEG][D_STATE];

    const float An0 = -fexp(A_log[(long)d * D_STATE + n0]);
    const float An1 = -fexp(A_log[(long)d * D_STATE + n0 + 1]);

    const float* dtp = dtT + ((long)cd << 9) + w * SEGL;
    const float* up  = uT  + ((long)cd << 9) + w * SEGL;
    const float* blp = dbl + ((long)(b * L_SEQ + w * SEGL)) * DBL_LD + DT_RANK + n0;
    const float* clp = blp + D_STATE;

    if (w < NSEG - 1) {
        float h0 = 0.f, h1 = 0.f, sdt = 0.f;
        for (int s = 0; s < SEGL / 8; ++s) {
            const float4 dt0 = *(const float4*)(dtp + s * 8);
            const float4 dt1 = *(const float4*)(dtp + s * 8 + 4);
            const float4 u0  = *(const float4*)(up + s * 8);
            const float4 u1  = *(const float4*)(up + s * 8 + 4);
            float2 Bv[8];
#pragma unroll
            for (int j = 0; j < 8; ++j)
                Bv[j] = *(const float2*)(blp + (long)(s * 8 + j) * DBL_LD);
            const float dts[8] = {dt0.x, dt0.y, dt0.z, dt0.w, dt1.x, dt1.y, dt1.z, dt1.w};
            const float us[8]  = {u0.x,  u0.y,  u0.z,  u0.w,  u1.x,  u1.y,  u1.z,  u1.w};
#pragma unroll
            for (int j = 0; j < 8; ++j) {
                const float dtv = dts[j];
                sdt += dtv;
                const float dtu = dtv * us[j];
                h0 = fmaf(fexp(dtv * An0), h0, dtu * Bv[j].x);
                h1 = fmaf(fexp(dtv * An1), h1, dtu * Bv[j].y);
            }
        }
        Sh[w][n0] = h0; Sh[w][n0 + 1] = h1;
        Ph[w][n0] = fexp(An0 * sdt); Ph[w][n0 + 1] = fexp(An1 * sdt);
    }
    __syncthreads();

    float h0 = 0.f, h1 = 0.f;
    for (int s = 0; s < w; ++s) {
        h0 = fmaf(Ph[s][n0],     h0, Sh[s][n0]);
        h1 = fmaf(Ph[s][n0 + 1], h1, Sh[s][n0 + 1]);
    }

    float* ysp = ysT + ((long)cd << 9) + w * SEGL;
    for (int s = 0; s < SEGL / 8; ++s) {
        const float4 dt0 = *(const float4*)(dtp + s * 8);
        const float4 dt1 = *(const float4*)(dtp + s * 8 + 4);
        const float4 u0  = *(const float4*)(up + s * 8);
        const float4 u1  = *(const float4*)(up + s * 8 + 4);
        float2 Bv[8], Cv[8];
#pragma unroll
        for (int j = 0; j < 8; ++j) {
            Bv[j] = *(const float2*)(blp + (long)(s * 8 + j) * DBL_LD);
            Cv[j] = *(const float2*)(clp + (long)(s * 8 + j) * DBL_LD);
        }
        const float dts[8] = {dt0.x, dt0.y, dt0.z, dt0.w, dt1.x, dt1.y, dt1.z, dt1.w};
        const float us[8]  = {u0.x,  u0.y,  u0.z,  u0.w,  u1.x,  u1.y,  u1.z,  u1.w};
        float yp[8];
#pragma unroll
        for (int j = 0; j < 8; ++j) {
            const float dtv = dts[j];
            const float dtu = dtv * us[j];
            h0 = fmaf(fexp(dtv * An0), h0, dtu * Bv[j].x);
            h1 = fmaf(fexp(dtv * An1), h1, dtu * Bv[j].y);
            yp[j] = fmaf(h0, Cv[j].x, h1 * Cv[j].y);
        }
#pragma unroll
        for (int j = 0; j < 8; ++j) yp[j] = dpp_sum64(yp[j]);

        if (lane == 63) {
            *(float4*)(ysp + s * 8)     = (float4){yp[0], yp[1], yp[2], yp[3]};
            *(float4*)(ysp + s * 8 + 4) = (float4){yp[4], yp[5], yp[6], yp[7]};
        }
    }
}

// ---------------------------------------------------------------------------
// Fused double-transpose gate: y[row][d] = (ysT + uT*Dp) * silu(z) -> bf16
// ---------------------------------------------------------------------------
__global__ __launch_bounds__(256) void gate_kernel(
    const float* __restrict__ ysT, const float* __restrict__ uT,
    const float* __restrict__ Dp, const float* __restrict__ xz,
    bf16* __restrict__ y)
{
    __shared__ float t[64][65];
    __shared__ float t2[64][65];
    const int db = blockIdx.x;
    const int lb = blockIdx.y;
    const int b  = blockIdx.z;
    const int tid = threadIdx.x;
    const int r  = tid >> 4;
    const int c4 = (tid & 15) * 4;

#pragma unroll
    for (int q = 0; q < 4; ++q) {
        const int dr = r + q * 16;
        const long base = (((long)(b * D_INNER + db * 64 + dr)) << 9) + lb * 64 + c4;
        const float4 v = *(const float4*)&ysT[base];
        const float4 w = *(const float4*)&uT[base];
        t[dr][c4 + 0] = v.x; t[dr][c4 + 1] = v.y;
        t[dr][c4 + 2] = v.z; t[dr][c4 + 3] = v.w;
        t2[dr][c4 + 0] = w.x; t2[dr][c4 + 1] = w.y;
        t2[dr][c4 + 2] = w.z; t2[dr][c4 + 3] = w.w;
    }
    __syncthreads();

    const float4 dp4 = *(const float4*)&Dp[db * 64 + c4];
#pragma unroll
    for (int q = 0; q < 4; ++q) {
        const int lr = r + q * 16;
        const long row = (long)b * L_SEQ + lb * 64 + lr;
        const float4 z4 = *(const float4*)&xz[row * 2 * D_INNER + D_INNER + db * 64 + c4];
        const float r0 = (t[c4 + 0][lr] + t2[c4 + 0][lr] * dp4.x) * silu_f(z4.x);
        const float r1 = (t[c4 + 1][lr] + t2[c4 + 1][lr] * dp4.y) * silu_f(z4.y);
        const float r2 = (t[c4 + 2][lr] + t2[c4 + 2][lr] * dp4.z) * silu_f(z4.z);
        const float r3 = (t[c4 + 3][lr] + t2[c4 + 3][lr] * dp4.w) * silu_f(z4.w);
        bf16 b0 = __float2bfloat16(r0), b1 = __float2bfloat16(r1);
        bf16 b2 = __float2bfloat16(r2), b3 = __float2bfloat16(r3);
        ushort4 pk;
        pk.x = *reinterpret_cast<unsigned short*>(&b0);
        pk.y = *reinterpret_cast<unsigned short*>(&b1);
        pk.z = *reinterpret_cast<unsigned short*>(&b2);
        pk.w = *reinterpret_cast<unsigned short*>(&b3);
        *reinterpret_cast<ushort4*>(y + row * D_INNER + db * 64 + c4) = pk;
    }
}

// ---------------------------------------------------------------------------
// Flash-style cross-attention, QT=16, 16-way k-split -> 512 blocks (2/CU).
// ---------------------------------------------------------------------------
#define QT 16
#define CK 64

__global__ __launch_bounds__(256) void attn_kernel(
    const float* __restrict__ q, const float* __restrict__ k,
    const float* __restrict__ v, bf16* __restrict__ o)
{
    const int qt = blockIdx.x;
    const int hh = blockIdx.y;
    const int b  = blockIdx.z;
    const int t = threadIdx.x;
    const int lane = t & 15;
    const int qa = t >> 4;
    const int q0 = qt * QT + qa;

    __shared__ float Ks[CK][36];
    __shared__ float Vs[CK][36];

    const float scale = 0.17677669529663687f;
    float qr0[32];
    {
        const float* q0p = q + ((long)(b * L_SEQ + q0) * D_MODEL + hh * DK);
#pragma unroll
        for (int i = 0; i < 8; ++i) {
            const float4 a = *(const float4*)&q0p[i * 4];
            qr0[i*4+0] = a.x * scale; qr0[i*4+1] = a.y * scale;
            qr0[i*4+2] = a.z * scale; qr0[i*4+3] = a.w * scale;
        }
    }

    float m0 = -1e30f, l0 = 0.f, o0[32] = {};

    for (int c = 0; c < L_SEQ; c += CK) {
        __syncthreads();
        {
            const int fid = t * 2;
            const int row = fid >> 3;
            const int c0  = (fid & 7) * 4;
            const float* kp = k + ((long)(b * L_SEQ + c + row) * D_MODEL + hh * DK + c0);
            const float* vp = v + ((long)(b * L_SEQ + c + row) * D_MODEL + hh * DK + c0);
            *(float4*)&Ks[row][c0]     = *(const float4*)kp;
            *(float4*)&Ks[row][c0 + 4] = *(const float4*)(kp + 4);
            *(float4*)&Vs[row][c0]     = *(const float4*)vp;
            *(float4*)&Vs[row][c0 + 4] = *(const float4*)(vp + 4);
        }
        __syncthreads();

        float s0[4];
#pragma unroll
        for (int i = 0; i < 4; ++i) {
            const int kk = i * 16 + lane;
            float a0 = 0.f;
#pragma unroll
            for (int dd = 0; dd < 32; dd += 4) {
                const float4 kv = *(const float4*)&Ks[kk][dd];
                a0 = fmaf(qr0[dd+0], kv.x, a0); a0 = fmaf(qr0[dd+1], kv.y, a0);
                a0 = fmaf(qr0[dd+2], kv.z, a0); a0 = fmaf(qr0[dd+3], kv.w, a0);
            }
            s0[i] = a0;
        }

        float cm0 = s0[0];
#pragma unroll
        for (int i = 1; i < 4; ++i) cm0 = fmaxf(cm0, s0[i]);
#pragma unroll
        for (int off = 8; off > 0; off >>= 1)
            cm0 = fmaxf(cm0, __shfl_down(cm0, off, 16));
        cm0 = __shfl(cm0, 0, 16);

        const float nm0 = fmaxf(m0, cm0);
        const float al0 = fexp(m0 - nm0);
        l0 *= al0;
#pragma unroll
        for (int dd = 0; dd < 32; ++dd) o0[dd] *= al0;
        m0 = nm0;

        float p0[4];
#pragma unroll
        for (int i = 0; i < 4; ++i) { p0[i] = fexp(s0[i] - m0); l0 += p0[i]; }

#pragma unroll
        for (int i = 0; i < 4; ++i) {
            const int kk = i * 16 + lane;
#pragma unroll
            for (int dd = 0; dd < 32; dd += 4) {
                const float4 vv = *(const float4*)&Vs[kk][dd];
                o0[dd+0] = fmaf(p0[i], vv.x, o0[dd+0]);
                o0[dd+1] = fmaf(p0[i], vv.y, o0[dd+1]);
                o0[dd+2] = fmaf(p0[i], vv.z, o0[dd+2]);
                o0[dd+3] = fmaf(p0[i], vv.w, o0[dd+3]);
            }
        }
    }

#pragma unroll
    for (int off = 8; off > 0; off >>= 1) {
        l0 += __shfl_down(l0, off, 16);
#pragma unroll
        for (int dd = 0; dd < 32; ++dd) o0[dd] += __shfl_down(o0[dd], off, 16);
    }
    if (lane == 0) {
        const float i0 = 1.f / l0;
        bf16* op0 = o + ((long)(b * L_SEQ + q0) * D_MODEL + hh * DK);
#pragma unroll
        for (int dd = 0; dd < 32; ++dd) op0[dd] = __float2bfloat16(o0[dd] * i0);
    }
}

// ---------------------------------------------------------------------------

extern "C" void kernel_launch(void* const* d_in, const int* in_sizes, int n_in,
                              void* d_out, int out_size, void* d_ws, size_t ws_size,
                              hipStream_t stream) {
    const float* X   = (const float*)d_in[0];
    const float* MEM = (const float*)d_in[1];
    const float* CW  = (const float*)d_in[5];
    const float* CB  = (const float*)d_in[6];
    const float* DTW = (const float*)d_in[8];
    const float* DTB = (const float*)d_in[9];
    const float* ALG = (const float*)d_in[10];
    const float* DP  = (const float*)d_in[11];
    const float* N1A = (const float*)d_in[13];
    const float* N1B = (const float*)d_in[14];
    const float* N2A = (const float*)d_in[15];
    const float* N2B = (const float*)d_in[16];
    const float* N3A = (const float*)d_in[17];
    const float* N3B = (const float*)d_in[18];
    const float* WQB = (const float*)d_in[20];
    const float* WKB = (const float*)d_in[22];
    const float* WVB = (const float*)d_in[24];
    const float* WOB = (const float*)d_in[26];
    const float* W1B = (const float*)d_in[28];
    const float* W2B = (const float*)d_in[30];
    const float* INW = (const float*)d_in[4];
    const float* XPW = (const float*)d_in[7];
    const float* OPW = (const float*)d_in[12];
    const float* WQ  = (const float*)d_in[19];
    const float* WKw = (const float*)d_in[21];
    const float* WVw = (const float*)d_in[23];
    const float* WO  = (const float*)d_in[25];
    const float* W1  = (const float*)d_in[27];
    const float* W2  = (const float*)d_in[29];
    float* out = (float*)d_out;

    // ---- bf16 arena ----
    bf16* bp = (bf16*)d_ws;
    bf16* ub   = bp;  bp += (long)R_TOT * D_INNER;
    bf16* ybb  = bp;  bp += (long)R_TOT * D_INNER;
    bf16* ffab = ybb;
    bf16* ln1b = bp;  bp += (long)R_TOT * D_MODEL;
    bf16* aob  = ln1b;
    bf16* ln2b = bp;  bp += (long)R_TOT * D_MODEL;
    bf16* ln3b = ln2b;
    bf16* arena = bp; bp += S_TOT;
    bf16* MEMb = arena;
    bf16* INWb = MEMb + S_MEM;
    bf16* XPWb = INWb + S_INW;
    bf16* OPWb = XPWb + S_XPW;
    bf16* WQb  = OPWb + S_OPW;
    bf16* WKb  = WQb + S_WQ;
    bf16* WVb  = WKb + S_WK;
    bf16* WOb  = WVb + S_WV;
    bf16* W1b  = WOb + S_WO;
    bf16* W2b  = W1b + S_W1;

    // ---- f32 buffers (h1,qb,kb,vb contiguous for one-shot zeroing) ----
    float* p = (float*)(bp + ((((long)(bp - (bf16*)d_ws)) & 1) ? 1 : 0));
    float* xz  = p;                                  p += (long)R_TOT * 2 * D_INNER;
    float* uT  = p;                                  p += (long)R_TOT * D_INNER;
    float* dbl = p;                                  p += (long)R_TOT * DBL_LD;
    float* dtT = p;                                  p += (long)R_TOT * D_INNER;
    float* ysT = p;                                  p += (long)R_TOT * D_INNER;
    float* h1  = p;                                  p += (long)R_TOT * D_MODEL;
    float* qb  = p;                                  p += (long)R_TOT * D_MODEL;
    float* kb  = p;                                  p += (long)R_TOT * D_MODEL;
    float* vb  = p;                                  p += (long)R_TOT * D_MODEL;
    float* h2  = p;                                  p += (long)R_TOT * D_MODEL;

    const dim3 blk256(256);
    const int MT64 = R_TOT / 64;   // 16

    // 0. pack weights + memory to bf16 + ln1 + zero h1/qb/kb/vb/out/dbl
    pack_ln1<<<PACK_BLKS + R_TOT + ZERO_BLKS, blk256, 0, stream>>>(
        MEM, INW, XPW, OPW, WQ, WKw, WVw, WO, W1, W2, arena,
        X, N1A, N1B, ln1b, h1, out, dbl);

    // 1. xz = ln1 @ in_proj^T   [R,2048] f32
    mfma_gemm<0><<<dim3(2 * D_INNER / 64, MT64), blk256, 0, stream>>>(
        ln1b, INWb, D_MODEL, xz, nullptr, 2 * D_INNER, nullptr, nullptr,
        R_TOT, 2 * D_INNER);

    // 2. conv+silu -> ub (bf16) + uT (f32 transposed)
    conv_silu_T<<<dim3(D_INNER / 64, L_SEQ / 64, B_SZ), blk256, 0, stream>>>(
        xz, CW, CB, ub, uT);

    // 3. dbl = u @ x_proj^T  [R,272] (split-K=4, 320 blocks, atomic f32)
    splitk_gemm<4><<<dim3((DBL_LD + 63) / 64, MT64, 4), blk256, 0, stream>>>(
        ub, XPWb, D_INNER, dbl, DBL_LD, nullptr, nullptr, R_TOT, DBL_LD);

    // 4. dt = softplus(dbl[:,:16] @ dt_proj^T + b) -> dtT directly
    dt_gemm_T<<<dim3(D_INNER / 64, MT64), blk256, 0, stream>>>(dbl, DTW, DTB, dtT);

    // 5. fused segmented scan -> ysT
    scan_fused<<<B_SZ * D_INNER, dim3(1024), 0, stream>>>(dtT, uT, dbl, ALG, ysT);

    // 6. gate (double transpose) -> bf16 y[row][d]
    gate_kernel<<<dim3(D_INNER / 64, L_SEQ / 64, B_SZ), blk256, 0, stream>>>(
        ysT, uT, DP, xz, ybb);

    // 7. h1 = x + y @ out_proj^T  (split-K=4, 256 blocks, atomic f32)
    splitk_gemm<4><<<dim3(D_MODEL / 64, MT64, 4), blk256, 0, stream>>>(
        ybb, OPWb, D_INNER, h1, D_MODEL, nullptr, X, R_TOT, D_MODEL);

    // 8. ln2 -> bf16
    ln_kernel<<<R_TOT, blk256, 0, stream>>>(h1, N2A, N2B, ln2b);

    // 9. q,k,v (split-K=2, 384 blocks, atomic f32)
    qkv_gemm<<<dim3(D_MODEL / 64, MT64, 6), blk256, 0, stream>>>(
        ln2b, MEMb, WQb, WKb, WVb, WQB, WKB, WVB, qb, kb, vb);

    // 10. attention -> bf16 (512 blocks)
    attn_kernel<<<dim3(L_SEQ / QT, N_HEADS, B_SZ), blk256, 0, stream>>>(qb, kb, vb, aob);

    // 11. h2 = h1 + ao @ wo^T + wo_b (f32) + fused LN3 -> bf16 (K=256)
    gemm16_ln<<<R_TOT / 16, blk256, 0, stream>>>(
        aob, WOb, D_MODEL, WOB, h1, h2, N3A, N3B, ln3b);

    // 12. ffa = relu(ln3 @ w1^T + b) -> bf16
    mfma_gemm<1><<<dim3(D_FF / 64, MT64), blk256, 0, stream>>>(
        ln3b, W1b, D_MODEL, nullptr, ffab, D_FF, W1B, nullptr, R_TOT, D_FF);

    // 13. out = h2 + ffa @ w2^T + b  (split-K=4, 256 blocks, atomic f32)
    splitk_gemm<4><<<dim3(D_MODEL / 64, MT64, 4), blk256, 0, stream>>>(
        ffab, W2b, D_FF, out, D_MODEL, W2B, h2, R_TOT, D_MODEL);

    (void)in_sizes; (void)n_in; (void)out_size; (void)ws_size;
}

// Round 17
// 379.174 us; speedup vs baseline: 1.0614x; 1.0053x over previous
//
#include <hip/hip_runtime.h>
#include <hip/hip_bf16.h>

// Problem dims (fixed)
#define B_SZ 2
#define L_SEQ 512
#define D_MODEL 256
#define D_STATE 128
#define D_CONV 4
#define D_INNER 1024
#define DT_RANK 16
#define N_HEADS 8
#define DK 32
#define D_FF 1024
#define R_TOT (B_SZ * L_SEQ)   // 1024 rows
#define DBL_LD (DT_RANK + 2 * D_STATE)  // 272
#define NSEG 16
#define SEGL 32   // L_SEQ / NSEG

typedef __hip_bfloat16 bf16;
typedef __attribute__((ext_vector_type(8))) short short8;   // 8 bf16 = 4 VGPR
typedef __attribute__((ext_vector_type(4))) float floatx4;

// Fast transcendentals (native v_exp/v_log/v_rcp; 1-4 ULP, self-damping in scan)
__device__ inline float fexp(float x) { return __expf(x); }
__device__ inline float frcp(float x) { return __builtin_amdgcn_rcpf(x); }
__device__ inline float silu_f(float x) { return x * frcp(1.f + fexp(-x)); }
__device__ inline float softplus_f(float x) { return (x > 20.f) ? x : __logf(1.f + fexp(x)); }
__device__ inline float bf2f(unsigned short u) { return __uint_as_float(((unsigned)u) << 16); }

// 64-lane sum via DPP (VALU pipe, no DS traffic). Result valid in lane 63.
__device__ inline float dpp_sum64(float x) {
    x += __int_as_float(__builtin_amdgcn_update_dpp(0, __float_as_int(x), 0x111, 0xf, 0xf, true));
    x += __int_as_float(__builtin_amdgcn_update_dpp(0, __float_as_int(x), 0x112, 0xf, 0xf, true));
    x += __int_as_float(__builtin_amdgcn_update_dpp(0, __float_as_int(x), 0x114, 0xf, 0xf, true));
    x += __int_as_float(__builtin_amdgcn_update_dpp(0, __float_as_int(x), 0x118, 0xf, 0xf, true));
    x += __int_as_float(__builtin_amdgcn_update_dpp(0, __float_as_int(x), 0x142, 0xf, 0xf, true));
    x += __int_as_float(__builtin_amdgcn_update_dpp(0, __float_as_int(x), 0x143, 0xf, 0xf, true));
    return x;
}

// ---------------------------------------------------------------------------
// Dispatch 0: pack (mem + 9 weights f32->bf16) + LN1 + zero-fill of all
// atomically-accumulated buffers (h1,qb,kb,vb 4 MB; out 1 MB; dbl 1.1 MB).
// ---------------------------------------------------------------------------
#define S_MEM 262144
#define S_INW 524288
#define S_XPW 278528
#define S_OPW 262144
#define S_WQ  65536
#define S_WK  65536
#define S_WV  65536
#define S_WO  65536
#define S_W1  262144
#define S_W2  262144
#define S_TOT (S_MEM+S_INW+S_XPW+S_OPW+S_WQ+S_WK+S_WV+S_WO+S_W1+S_W2)
#define PACK_BLKS ((S_TOT + 255) / 256)
#define Z1_F4 (4 * R_TOT * D_MODEL / 4)   // h1+qb+kb+vb float4 count
#define Z2_F4 (R_TOT * D_MODEL / 4)       // out float4 count
#define Z3_F4 (R_TOT * DBL_LD / 4)        // dbl float4 count
#define ZERO_BLKS ((Z1_F4 + Z2_F4 + Z3_F4 + 255) / 256)

__global__ __launch_bounds__(256) void pack_ln1(
    const float* __restrict__ s0, const float* __restrict__ s1,
    const float* __restrict__ s2, const float* __restrict__ s3,
    const float* __restrict__ s4, const float* __restrict__ s5,
    const float* __restrict__ s6, const float* __restrict__ s7,
    const float* __restrict__ s8, const float* __restrict__ s9,
    bf16* __restrict__ dst,
    const float* __restrict__ X, const float* __restrict__ a,
    const float* __restrict__ bvec, bf16* __restrict__ ln1b,
    float* __restrict__ zero1, float* __restrict__ zero2,
    float* __restrict__ zero3)
{
    __shared__ float r1[256], r2[256];
    if (blockIdx.x < PACK_BLKS) {
        const long i = (long)blockIdx.x * 256 + threadIdx.x;
        if (i >= S_TOT) return;
        const long off[11] = {0, S_MEM, S_MEM+S_INW, S_MEM+S_INW+S_XPW,
            S_MEM+S_INW+S_XPW+S_OPW, S_MEM+S_INW+S_XPW+S_OPW+S_WQ,
            S_MEM+S_INW+S_XPW+S_OPW+S_WQ+S_WK,
            S_MEM+S_INW+S_XPW+S_OPW+S_WQ+S_WK+S_WV,
            S_MEM+S_INW+S_XPW+S_OPW+S_WQ+S_WK+S_WV+S_WO,
            S_MEM+S_INW+S_XPW+S_OPW+S_WQ+S_WK+S_WV+S_WO+S_W1, S_TOT};
        const float* srcs[10] = {s0,s1,s2,s3,s4,s5,s6,s7,s8,s9};
        int seg = 0;
#pragma unroll
        for (int k = 1; k < 10; ++k) if (i >= off[k]) seg = k;
        dst[i] = __float2bfloat16(srcs[seg][i - off[seg]]);
    } else if (blockIdx.x < PACK_BLKS + R_TOT) {
        const int row = blockIdx.x - PACK_BLKS;
        const int t = threadIdx.x;
        const float v = X[(long)row * D_MODEL + t];
        r1[t] = v;
        r2[t] = v * v;
        __syncthreads();
        for (int s = 128; s > 0; s >>= 1) {
            if (t < s) { r1[t] += r1[t + s]; r2[t] += r2[t + s]; }
            __syncthreads();
        }
        const float mean = r1[0] * (1.f / 256.f);
        const float var = (r2[0] - 256.f * mean * mean) * (1.f / 255.f);
        const float sd = sqrtf(fmaxf(var, 0.f));
        const float o = a[t] * (v - mean) / (sd + 1e-6f) + bvec[t];
        ln1b[(long)row * D_MODEL + t] = __float2bfloat16(o);
    } else {
        const long i4 = (long)(blockIdx.x - PACK_BLKS - R_TOT) * 256 + threadIdx.x;
        const float4 z = {0.f, 0.f, 0.f, 0.f};
        if (i4 < Z1_F4)                      *(float4*)&zero1[i4 * 4] = z;
        else if (i4 < Z1_F4 + Z2_F4)          *(float4*)&zero2[(i4 - Z1_F4) * 4] = z;
        else if (i4 < Z1_F4 + Z2_F4 + Z3_F4)  *(float4*)&zero3[(i4 - Z1_F4 - Z2_F4) * 4] = z;
    }
}

// ---------------------------------------------------------------------------
// MFMA GEMM: C = epi(A @ W^T + bias)(+res), bf16 inputs, f32/bf16 out.
// ---------------------------------------------------------------------------
template <int EPI>
__global__ __launch_bounds__(256) void mfma_gemm(
    const bf16* __restrict__ A, const bf16* __restrict__ W, int K,
    float* __restrict__ C, bf16* __restrict__ Cb, int ldc,
    const float* __restrict__ bias, const float* __restrict__ res,
    int M, int N)
{
    const int wave = threadIdx.x >> 6;
    const int lane = threadIdx.x & 63;
    const int row16 = lane & 15;
    const int quad  = lane >> 4;
    const int bm = blockIdx.y * 64 + wave * 16;
    const int bn = blockIdx.x * 64;

    floatx4 acc[4];
#pragma unroll
    for (int t = 0; t < 4; ++t) acc[t] = (floatx4){0.f, 0.f, 0.f, 0.f};

    const long arow = (long)(bm + row16) * K;
    for (int k0 = 0; k0 < K; k0 += 32) {
        const short8 av = *(const short8*)(A + arow + k0 + quad * 8);
#pragma unroll
        for (int t = 0; t < 4; ++t) {
            const int gn = bn + t * 16 + row16;
            short8 bv = {0,0,0,0,0,0,0,0};
            if (gn < N) bv = *(const short8*)(W + (long)gn * K + k0 + quad * 8);
            acc[t] = __builtin_amdgcn_mfma_f32_16x16x32_bf16(av, bv, acc[t], 0, 0, 0);
        }
    }

#pragma unroll
    for (int t = 0; t < 4; ++t) {
        const int gn = bn + t * 16 + row16;
        if (gn >= N) continue;
        const float bs = bias ? bias[gn] : 0.f;
#pragma unroll
        for (int r = 0; r < 4; ++r) {
            const int gm = bm + quad * 4 + r;
            float v = acc[t][r] + bs;
            if (EPI == 1) v = fmaxf(v, 0.f);
            const long ci = (long)gm * ldc + gn;
            if (res) v += res[ci];
            if (C)  C[ci] = v;
            if (Cb) Cb[ci] = __float2bfloat16(v);
        }
    }
}

// ---------------------------------------------------------------------------
// Split-K MFMA GEMM (h1 out_proj, w2): atomicAdd into pre-zeroed f32 C.
// ---------------------------------------------------------------------------
template <int SK>
__global__ __launch_bounds__(256) void splitk_gemm(
    const bf16* __restrict__ A, const bf16* __restrict__ W, int K,
    float* __restrict__ C, int ldc,
    const float* __restrict__ bias, const float* __restrict__ res,
    int M, int N)
{
    const int wave = threadIdx.x >> 6;
    const int lane = threadIdx.x & 63;
    const int row16 = lane & 15;
    const int quad  = lane >> 4;
    const int bm = blockIdx.y * 64 + wave * 16;
    const int bn = blockIdx.x * 64;
    const int kz = blockIdx.z;
    const int ksl = K / SK;
    const int kbeg = kz * ksl;

    floatx4 acc[4];
#pragma unroll
    for (int t = 0; t < 4; ++t) acc[t] = (floatx4){0.f, 0.f, 0.f, 0.f};

    const long arow = (long)(bm + row16) * K;
    for (int k0 = kbeg; k0 < kbeg + ksl; k0 += 32) {
        const short8 av = *(const short8*)(A + arow + k0 + quad * 8);
#pragma unroll
        for (int t = 0; t < 4; ++t) {
            const int gn = bn + t * 16 + row16;
            short8 bv = {0,0,0,0,0,0,0,0};
            if (gn < N) bv = *(const short8*)(W + (long)gn * K + k0 + quad * 8);
            acc[t] = __builtin_amdgcn_mfma_f32_16x16x32_bf16(av, bv, acc[t], 0, 0, 0);
        }
    }

#pragma unroll
    for (int t = 0; t < 4; ++t) {
        const int gn = bn + t * 16 + row16;
        if (gn >= N) continue;
        const float bs = (kz == 0 && bias) ? bias[gn] : 0.f;
#pragma unroll
        for (int r = 0; r < 4; ++r) {
            const int gm = bm + quad * 4 + r;
            float v = acc[t][r] + bs;
            const long ci = (long)gm * ldc + gn;
            if (kz == 0 && res) v += res[ci];
            atomicAdd(&C[ci], v);
        }
    }
}

// ---------------------------------------------------------------------------
// x_proj (split-K=4) + k/v (split-K=2) merged: grid (5, 16, 8).
// z<4: dbl += ub@XPW^T slice kz=z.  z>=4: kv: which=(z-4)>>1, kz=(z-4)&1.
// All atomicAdd into pre-zeroed buffers; k/v depend only on dispatch 0.
// ---------------------------------------------------------------------------
__global__ __launch_bounds__(256) void xproj_kv_gemm(
    const bf16* __restrict__ ub, const bf16* __restrict__ XPWb,
    float* __restrict__ dbl,
    const bf16* __restrict__ memb, const bf16* __restrict__ WKb,
    const bf16* __restrict__ WVb,
    const float* __restrict__ WKB, const float* __restrict__ WVB,
    float* __restrict__ kb, float* __restrict__ vb)
{
    const int wave = threadIdx.x >> 6;
    const int lane = threadIdx.x & 63;
    const int row16 = lane & 15;
    const int quad  = lane >> 4;
    const int bm = blockIdx.y * 64 + wave * 16;
    const int bn = blockIdx.x * 64;
    const int z = blockIdx.z;

    const bf16* A; const bf16* W; const float* bias; float* C;
    int K, N, ldc, kbeg, ksl;
    if (z < 4) {
        A = ub; W = XPWb; bias = nullptr; C = dbl;
        K = D_INNER; N = DBL_LD; ldc = DBL_LD;
        ksl = D_INNER / 4; kbeg = z * ksl;
    } else {
        if (bn >= D_MODEL) return;
        const int zz = z - 4;
        const int which = zz >> 1;
        const int kz = zz & 1;
        A = memb; W = which ? WVb : WKb;
        bias = (kz == 0) ? (which ? WVB : WKB) : nullptr;
        C = which ? vb : kb;
        K = D_MODEL; N = D_MODEL; ldc = D_MODEL;
        ksl = D_MODEL / 2; kbeg = kz * ksl;
    }

    floatx4 acc[4];
#pragma unroll
    for (int t = 0; t < 4; ++t) acc[t] = (floatx4){0.f, 0.f, 0.f, 0.f};

    const long arow = (long)(bm + row16) * K;
    for (int k0 = kbeg; k0 < kbeg + ksl; k0 += 32) {
        const short8 av = *(const short8*)(A + arow + k0 + quad * 8);
#pragma unroll
        for (int t = 0; t < 4; ++t) {
            const int gn = bn + t * 16 + row16;
            short8 bv = {0,0,0,0,0,0,0,0};
            if (gn < N) bv = *(const short8*)(W + (long)gn * K + k0 + quad * 8);
            acc[t] = __builtin_amdgcn_mfma_f32_16x16x32_bf16(av, bv, acc[t], 0, 0, 0);
        }
    }

#pragma unroll
    for (int t = 0; t < 4; ++t) {
        const int gn = bn + t * 16 + row16;
        if (gn >= N) continue;
        const float bs = bias ? bias[gn] : 0.f;
#pragma unroll
        for (int r = 0; r < 4; ++r) {
            const int gm = bm + quad * 4 + r;
            atomicAdd(&C[(long)gm * ldc + gn], acc[t][r] + bs);
        }
    }
}

// ---------------------------------------------------------------------------
// q-only GEMM (split-K=2): grid (4, 16, 2). atomicAdd into pre-zeroed qb.
// ---------------------------------------------------------------------------
__global__ __launch_bounds__(256) void q_gemm(
    const bf16* __restrict__ ln2b, const bf16* __restrict__ WQb,
    const float* __restrict__ WQB, float* __restrict__ qb)
{
    const int wave = threadIdx.x >> 6;
    const int lane = threadIdx.x & 63;
    const int row16 = lane & 15;
    const int quad  = lane >> 4;
    const int bm = blockIdx.y * 64 + wave * 16;
    const int bn = blockIdx.x * 64;
    const int kz = blockIdx.z;
    const int kbeg = kz * (D_MODEL / 2);

    floatx4 acc[4];
#pragma unroll
    for (int t = 0; t < 4; ++t) acc[t] = (floatx4){0.f, 0.f, 0.f, 0.f};

    const long arow = (long)(bm + row16) * D_MODEL;
    for (int k0 = kbeg; k0 < kbeg + D_MODEL / 2; k0 += 32) {
        const short8 av = *(const short8*)(ln2b + arow + k0 + quad * 8);
#pragma unroll
        for (int t = 0; t < 4; ++t) {
            const int gn = bn + t * 16 + row16;
            const short8 bv = *(const short8*)(WQb + (long)gn * D_MODEL + k0 + quad * 8);
            acc[t] = __builtin_amdgcn_mfma_f32_16x16x32_bf16(av, bv, acc[t], 0, 0, 0);
        }
    }
#pragma unroll
    for (int t = 0; t < 4; ++t) {
        const int gn = bn + t * 16 + row16;
        const float bs = (kz == 0) ? WQB[gn] : 0.f;
#pragma unroll
        for (int r = 0; r < 4; ++r) {
            const int gm = bm + quad * 4 + r;
            atomicAdd(&qb[(long)gm * D_MODEL + gn], acc[t][r] + bs);
        }
    }
}

// ---------------------------------------------------------------------------
// gemm16_ln: wo (K=256) + fused LN3. grid = M/16 blocks.
// ---------------------------------------------------------------------------
__global__ __launch_bounds__(256) void gemm16_ln(
    const bf16* __restrict__ A, const bf16* __restrict__ W, int K,
    const float* __restrict__ bias, const float* __restrict__ res,
    float* __restrict__ Cf,
    const float* __restrict__ lna, const float* __restrict__ lnb,
    bf16* __restrict__ lnout)
{
    __shared__ float tile[16][264];
    __shared__ float red1[16][16];
    __shared__ float red2[16][16];
    const int w = threadIdx.x >> 6;
    const int lane = threadIdx.x & 63;
    const int row16 = lane & 15;
    const int quad  = lane >> 4;
    const int bm = blockIdx.x * 16;

    floatx4 acc[4];
#pragma unroll
    for (int t = 0; t < 4; ++t) acc[t] = (floatx4){0.f, 0.f, 0.f, 0.f};

    const long arow = (long)(bm + row16) * K;
    for (int k0 = 0; k0 < K; k0 += 32) {
        const short8 av = *(const short8*)(A + arow + k0 + quad * 8);
#pragma unroll
        for (int t = 0; t < 4; ++t) {
            const int gn = w * 64 + t * 16 + row16;
            const short8 bv = *(const short8*)(W + (long)gn * K + k0 + quad * 8);
            acc[t] = __builtin_amdgcn_mfma_f32_16x16x32_bf16(av, bv, acc[t], 0, 0, 0);
        }
    }

#pragma unroll
    for (int t = 0; t < 4; ++t) {
        const int gn = w * 64 + t * 16 + row16;
        const float bs = bias ? bias[gn] : 0.f;
#pragma unroll
        for (int r = 0; r < 4; ++r) {
            const int gm = bm + quad * 4 + r;
            float v = acc[t][r] + bs;
            const long ci = (long)gm * D_MODEL + gn;
            if (res) v += res[ci];
            Cf[ci] = v;
            tile[quad * 4 + r][gn] = v;
        }
    }
    __syncthreads();

    const int r = threadIdx.x >> 4;
    const int g = threadIdx.x & 15;
    float s = 0.f, q = 0.f;
#pragma unroll
    for (int i = 0; i < 16; ++i) {
        const float x = tile[r][g * 16 + i];
        s += x; q += x * x;
    }
    red1[r][g] = s; red2[r][g] = q;
    __syncthreads();
    float ts = 0.f, tq = 0.f;
#pragma unroll
    for (int i = 0; i < 16; ++i) { ts += red1[r][i]; tq += red2[r][i]; }
    const float mean = ts * (1.f / 256.f);
    const float var = (tq - 256.f * mean * mean) * (1.f / 255.f);
    const float sd = sqrtf(fmaxf(var, 0.f));
    const long rowbase = (long)(bm + r) * D_MODEL;
#pragma unroll
    for (int i = 0; i < 16; ++i) {
        const int c = g * 16 + i;
        const float o = lna[c] * (tile[r][c] - mean) / (sd + 1e-6f) + lnb[c];
        lnout[rowbase + c] = __float2bfloat16(o);
    }
}

// ---------------------------------------------------------------------------
// LayerNorm -> bf16 (LN2 after split-K out_proj)
// ---------------------------------------------------------------------------
__global__ __launch_bounds__(256) void ln_kernel(
    const float* __restrict__ x, const float* __restrict__ a,
    const float* __restrict__ bvec, bf16* __restrict__ out)
{
    const int row = blockIdx.x;
    const int t = threadIdx.x;
    const float v = x[(long)row * D_MODEL + t];
    __shared__ float r1[256], r2[256];
    r1[t] = v;
    r2[t] = v * v;
    __syncthreads();
    for (int s = 128; s > 0; s >>= 1) {
        if (t < s) { r1[t] += r1[t + s]; r2[t] += r2[t + s]; }
        __syncthreads();
    }
    const float mean = r1[0] * (1.f / 256.f);
    const float var = (r2[0] - 256.f * mean * mean) * (1.f / 255.f);
    const float sd = sqrtf(fmaxf(var, 0.f));
    const float o = a[t] * (v - mean) / (sd + 1e-6f) + bvec[t];
    out[(long)row * D_MODEL + t] = __float2bfloat16(o);
}

// ---------------------------------------------------------------------------
// dt_proj GEMM (K=16) + softplus, writing TRANSPOSED output dtT[b][d][l].
// ---------------------------------------------------------------------------
__global__ __launch_bounds__(256) void dt_gemm_T(
    const float* __restrict__ A /*dbl*/, const float* __restrict__ W /*DTW*/,
    const float* __restrict__ bias, float* __restrict__ dtT)
{
    __shared__ float As[DT_RANK][65];
    __shared__ float Bs[DT_RANK][65];
    __shared__ float Ct[64][65];
    const int bm = blockIdx.y * 64;   // rows (b,l)
    const int bn = blockIdx.x * 64;   // d
    const int tid = threadIdx.x;
    const int tx = tid & 15;
    const int ty = tid >> 4;
    const int r = tid >> 2;
    const int kk = (tid & 3) * 4;
#pragma unroll
    for (int q = 0; q < 4; ++q) {
        As[kk + q][r] = A[(long)(bm + r) * DBL_LD + kk + q];
        Bs[kk + q][r] = W[(long)(bn + r) * DT_RANK + kk + q];
    }
    __syncthreads();
    float acc[4][4] = {};
#pragma unroll
    for (int k = 0; k < DT_RANK; ++k) {
        float a[4], bv[4];
#pragma unroll
        for (int i = 0; i < 4; ++i) a[i] = As[k][ty * 4 + i];
#pragma unroll
        for (int j = 0; j < 4; ++j) bv[j] = Bs[k][tx * 4 + j];
#pragma unroll
        for (int i = 0; i < 4; ++i)
#pragma unroll
            for (int j = 0; j < 4; ++j)
                acc[i][j] = fmaf(a[i], bv[j], acc[i][j]);
    }
#pragma unroll
    for (int i = 0; i < 4; ++i)
#pragma unroll
        for (int j = 0; j < 4; ++j)
            Ct[tx * 4 + j][ty * 4 + i] = softplus_f(acc[i][j] + bias[bn + tx * 4 + j]);
    __syncthreads();
    const int b = bm >> 9;
    const int l0 = bm & 511;
    const int r2 = tid >> 4;
    const int c4 = (tid & 15) * 4;
#pragma unroll
    for (int q = 0; q < 4; ++q) {
        const int dl = r2 + q * 16;
        float4 v = {Ct[dl][c4], Ct[dl][c4 + 1], Ct[dl][c4 + 2], Ct[dl][c4 + 3]};
        *(float4*)&dtT[((long)(b * D_INNER + bn + dl) << 9) + l0 + c4] = v;
    }
}

// ---------------------------------------------------------------------------
// Tiled causal conv(k=4)+SiLU over bf16 xz -> ub (bf16) + uT (f32 [b][d][l]).
// ---------------------------------------------------------------------------
__global__ __launch_bounds__(256) void conv_silu_T(
    const bf16* __restrict__ xz, const float* __restrict__ cw,
    const float* __restrict__ cb, bf16* __restrict__ ub, float* __restrict__ uT)
{
    __shared__ float t[64][65];
    const int db = blockIdx.x;
    const int lb = blockIdx.y;
    const int b  = blockIdx.z;
    const int tid = threadIdx.x;
    const int r  = tid >> 4;
    const int c4 = (tid & 15) * 4;
    const int d0 = db * 64 + c4;

    const float4 cb4 = *(const float4*)&cb[d0];
    float cwa[4][4];
#pragma unroll
    for (int i = 0; i < 4; ++i) {
        const float4 w = *(const float4*)&cw[(d0 + i) * 4];
        cwa[i][0] = w.x; cwa[i][1] = w.y; cwa[i][2] = w.z; cwa[i][3] = w.w;
    }

#pragma unroll
    for (int q = 0; q < 4; ++q) {
        const int ll = r + q * 16;
        const int l = lb * 64 + ll;
        float s0 = cb4.x, s1 = cb4.y, s2 = cb4.z, s3 = cb4.w;
#pragma unroll
        for (int k = 0; k < D_CONV; ++k) {
            const int ls = l - 3 + k;
            if (ls >= 0) {
                const ushort4 xv = *(const ushort4*)&xz[((long)(b * L_SEQ + ls)) * (2 * D_INNER) + d0];
                s0 = fmaf(bf2f(xv.x), cwa[0][k], s0);
                s1 = fmaf(bf2f(xv.y), cwa[1][k], s1);
                s2 = fmaf(bf2f(xv.z), cwa[2][k], s2);
                s3 = fmaf(bf2f(xv.w), cwa[3][k], s3);
            }
        }
        s0 = silu_f(s0); s1 = silu_f(s1); s2 = silu_f(s2); s3 = silu_f(s3);
        bf16 b0 = __float2bfloat16(s0), b1 = __float2bfloat16(s1);
        bf16 b2 = __float2bfloat16(s2), b3 = __float2bfloat16(s3);
        ushort4 pk;
        pk.x = *reinterpret_cast<unsigned short*>(&b0);
        pk.y = *reinterpret_cast<unsigned short*>(&b1);
        pk.z = *reinterpret_cast<unsigned short*>(&b2);
        pk.w = *reinterpret_cast<unsigned short*>(&b3);
        *reinterpret_cast<ushort4*>(ub + ((long)(b * L_SEQ + l)) * D_INNER + d0) = pk;
        t[c4 + 0][ll] = s0; t[c4 + 1][ll] = s1;
        t[c4 + 2][ll] = s2; t[c4 + 3][ll] = s3;
    }
    __syncthreads();
#pragma unroll
    for (int q = 0; q < 4; ++q) {
        const int dl = r + q * 16;
        float4 v = {t[dl][c4], t[dl][c4 + 1], t[dl][c4 + 2], t[dl][c4 + 3]};
        *(float4*)&uT[((long)(b * D_INNER + db * 64 + dl) << 9) + lb * 64 + c4] = v;
    }
}

// ---------------------------------------------------------------------------
// Fused segmented scan (frozen at its measured plateau ~140 us).
// ---------------------------------------------------------------------------
__global__ __launch_bounds__(1024) void scan_fused(
    const float* __restrict__ dtT, const float* __restrict__ uT,
    const float* __restrict__ dbl, const float* __restrict__ A_log,
    float* __restrict__ ysT)
{
    const int cd = blockIdx.x;            // b*1024 + d
    const int b = cd >> 10;
    const int d = cd & 1023;
    const int w = threadIdx.x >> 6;       // segment 0..15
    const int lane = threadIdx.x & 63;
    const int n0 = lane * 2;

    __shared__ float Sh[NSEG][D_STATE];
    __shared__ float Ph[NSEG][D_STATE];

    const float An0 = -fexp(A_log[(long)d * D_STATE + n0]);
    const float An1 = -fexp(A_log[(long)d * D_STATE + n0 + 1]);

    const float* dtp = dtT + ((long)cd << 9) + w * SEGL;
    const float* up  = uT  + ((long)cd << 9) + w * SEGL;
    const float* blp = dbl + ((long)(b * L_SEQ + w * SEGL)) * DBL_LD + DT_RANK + n0;
    const float* clp = blp + D_STATE;

    if (w < NSEG - 1) {
        float h0 = 0.f, h1 = 0.f, sdt = 0.f;
        for (int s = 0; s < SEGL / 8; ++s) {
            const float4 dt0 = *(const float4*)(dtp + s * 8);
            const float4 dt1 = *(const float4*)(dtp + s * 8 + 4);
            const float4 u0  = *(const float4*)(up + s * 8);
            const float4 u1  = *(const float4*)(up + s * 8 + 4);
            float2 Bv[8];
#pragma unroll
            for (int j = 0; j < 8; ++j)
                Bv[j] = *(const float2*)(blp + (long)(s * 8 + j) * DBL_LD);
            const float dts[8] = {dt0.x, dt0.y, dt0.z, dt0.w, dt1.x, dt1.y, dt1.z, dt1.w};
            const float us[8]  = {u0.x,  u0.y,  u0.z,  u0.w,  u1.x,  u1.y,  u1.z,  u1.w};
#pragma unroll
            for (int j = 0; j < 8; ++j) {
                const float dtv = dts[j];
                sdt += dtv;
                const float dtu = dtv * us[j];
                h0 = fmaf(fexp(dtv * An0), h0, dtu * Bv[j].x);
                h1 = fmaf(fexp(dtv * An1), h1, dtu * Bv[j].y);
            }
        }
        Sh[w][n0] = h0; Sh[w][n0 + 1] = h1;
        Ph[w][n0] = fexp(An0 * sdt); Ph[w][n0 + 1] = fexp(An1 * sdt);
    }
    __syncthreads();

    float h0 = 0.f, h1 = 0.f;
    for (int s = 0; s < w; ++s) {
        h0 = fmaf(Ph[s][n0],     h0, Sh[s][n0]);
        h1 = fmaf(Ph[s][n0 + 1], h1, Sh[s][n0 + 1]);
    }

    float* ysp = ysT + ((long)cd << 9) + w * SEGL;
    for (int s = 0; s < SEGL / 8; ++s) {
        const float4 dt0 = *(const float4*)(dtp + s * 8);
        const float4 dt1 = *(const float4*)(dtp + s * 8 + 4);
        const float4 u0  = *(const float4*)(up + s * 8);
        const float4 u1  = *(const float4*)(up + s * 8 + 4);
        float2 Bv[8], Cv[8];
#pragma unroll
        for (int j = 0; j < 8; ++j) {
            Bv[j] = *(const float2*)(blp + (long)(s * 8 + j) * DBL_LD);
            Cv[j] = *(const float2*)(clp + (long)(s * 8 + j) * DBL_LD);
        }
        const float dts[8] = {dt0.x, dt0.y, dt0.z, dt0.w, dt1.x, dt1.y, dt1.z, dt1.w};
        const float us[8]  = {u0.x,  u0.y,  u0.z,  u0.w,  u1.x,  u1.y,  u1.z,  u1.w};
        float yp[8];
#pragma unroll
        for (int j = 0; j < 8; ++j) {
            const float dtv = dts[j];
            const float dtu = dtv * us[j];
            h0 = fmaf(fexp(dtv * An0), h0, dtu * Bv[j].x);
            h1 = fmaf(fexp(dtv * An1), h1, dtu * Bv[j].y);
            yp[j] = fmaf(h0, Cv[j].x, h1 * Cv[j].y);
        }
#pragma unroll
        for (int j = 0; j < 8; ++j) yp[j] = dpp_sum64(yp[j]);

        if (lane == 63) {
            *(float4*)(ysp + s * 8)     = (float4){yp[0], yp[1], yp[2], yp[3]};
            *(float4*)(ysp + s * 8 + 4) = (float4){yp[4], yp[5], yp[6], yp[7]};
        }
    }
}

// ---------------------------------------------------------------------------
// Fused double-transpose gate: y[row][d] = (ysT + uT*Dp) * silu(z) -> bf16
// z read from bf16 xz.
// ---------------------------------------------------------------------------
__global__ __launch_bounds__(256) void gate_kernel(
    const float* __restrict__ ysT, const float* __restrict__ uT,
    const float* __restrict__ Dp, const bf16* __restrict__ xz,
    bf16* __restrict__ y)
{
    __shared__ float t[64][65];
    __shared__ float t2[64][65];
    const int db = blockIdx.x;
    const int lb = blockIdx.y;
    const int b  = blockIdx.z;
    const int tid = threadIdx.x;
    const int r  = tid >> 4;
    const int c4 = (tid & 15) * 4;

#pragma unroll
    for (int q = 0; q < 4; ++q) {
        const int dr = r + q * 16;
        const long base = (((long)(b * D_INNER + db * 64 + dr)) << 9) + lb * 64 + c4;
        const float4 v = *(const float4*)&ysT[base];
        const float4 w = *(const float4*)&uT[base];
        t[dr][c4 + 0] = v.x; t[dr][c4 + 1] = v.y;
        t[dr][c4 + 2] = v.z; t[dr][c4 + 3] = v.w;
        t2[dr][c4 + 0] = w.x; t2[dr][c4 + 1] = w.y;
        t2[dr][c4 + 2] = w.z; t2[dr][c4 + 3] = w.w;
    }
    __syncthreads();

    const float4 dp4 = *(const float4*)&Dp[db * 64 + c4];
#pragma unroll
    for (int q = 0; q < 4; ++q) {
        const int lr = r + q * 16;
        const long row = (long)b * L_SEQ + lb * 64 + lr;
        const ushort4 zu = *(const ushort4*)&xz[row * 2 * D_INNER + D_INNER + db * 64 + c4];
        const float r0 = (t[c4 + 0][lr] + t2[c4 + 0][lr] * dp4.x) * silu_f(bf2f(zu.x));
        const float r1 = (t[c4 + 1][lr] + t2[c4 + 1][lr] * dp4.y) * silu_f(bf2f(zu.y));
        const float r2 = (t[c4 + 2][lr] + t2[c4 + 2][lr] * dp4.z) * silu_f(bf2f(zu.z));
        const float r3 = (t[c4 + 3][lr] + t2[c4 + 3][lr] * dp4.w) * silu_f(bf2f(zu.w));
        bf16 b0 = __float2bfloat16(r0), b1 = __float2bfloat16(r1);
        bf16 b2 = __float2bfloat16(r2), b3 = __float2bfloat16(r3);
        ushort4 pk;
        pk.x = *reinterpret_cast<unsigned short*>(&b0);
        pk.y = *reinterpret_cast<unsigned short*>(&b1);
        pk.z = *reinterpret_cast<unsigned short*>(&b2);
        pk.w = *reinterpret_cast<unsigned short*>(&b3);
        *reinterpret_cast<ushort4*>(y + row * D_INNER + db * 64 + c4) = pk;
    }
}

// ---------------------------------------------------------------------------
// Flash-style cross-attention, QT=16, 16-way k-split -> 512 blocks (2/CU).
// ---------------------------------------------------------------------------
#define QT 16
#define CK 64

__global__ __launch_bounds__(256) void attn_kernel(
    const float* __restrict__ q, const float* __restrict__ k,
    const float* __restrict__ v, bf16* __restrict__ o)
{
    const int qt = blockIdx.x;
    const int hh = blockIdx.y;
    const int b  = blockIdx.z;
    const int t = threadIdx.x;
    const int lane = t & 15;
    const int qa = t >> 4;
    const int q0 = qt * QT + qa;

    __shared__ float Ks[CK][36];
    __shared__ float Vs[CK][36];

    const float scale = 0.17677669529663687f;
    float qr0[32];
    {
        const float* q0p = q + ((long)(b * L_SEQ + q0) * D_MODEL + hh * DK);
#pragma unroll
        for (int i = 0; i < 8; ++i) {
            const float4 a = *(const float4*)&q0p[i * 4];
            qr0[i*4+0] = a.x * scale; qr0[i*4+1] = a.y * scale;
            qr0[i*4+2] = a.z * scale; qr0[i*4+3] = a.w * scale;
        }
    }

    float m0 = -1e30f, l0 = 0.f, o0[32] = {};

    for (int c = 0; c < L_SEQ; c += CK) {
        __syncthreads();
        {
            const int fid = t * 2;
            const int row = fid >> 3;
            const int c0  = (fid & 7) * 4;
            const float* kp = k + ((long)(b * L_SEQ + c + row) * D_MODEL + hh * DK + c0);
            const float* vp = v + ((long)(b * L_SEQ + c + row) * D_MODEL + hh * DK + c0);
            *(float4*)&Ks[row][c0]     = *(const float4*)kp;
            *(float4*)&Ks[row][c0 + 4] = *(const float4*)(kp + 4);
            *(float4*)&Vs[row][c0]     = *(const float4*)vp;
            *(float4*)&Vs[row][c0 + 4] = *(const float4*)(vp + 4);
        }
        __syncthreads();

        float s0[4];
#pragma unroll
        for (int i = 0; i < 4; ++i) {
            const int kk = i * 16 + lane;
            float a0 = 0.f;
#pragma unroll
            for (int dd = 0; dd < 32; dd += 4) {
                const float4 kv = *(const float4*)&Ks[kk][dd];
                a0 = fmaf(qr0[dd+0], kv.x, a0); a0 = fmaf(qr0[dd+1], kv.y, a0);
                a0 = fmaf(qr0[dd+2], kv.z, a0); a0 = fmaf(qr0[dd+3], kv.w, a0);
            }
            s0[i] = a0;
        }

        float cm0 = s0[0];
#pragma unroll
        for (int i = 1; i < 4; ++i) cm0 = fmaxf(cm0, s0[i]);
#pragma unroll
        for (int off = 8; off > 0; off >>= 1)
            cm0 = fmaxf(cm0, __shfl_down(cm0, off, 16));
        cm0 = __shfl(cm0, 0, 16);

        const float nm0 = fmaxf(m0, cm0);
        const float al0 = fexp(m0 - nm0);
        l0 *= al0;
#pragma unroll
        for (int dd = 0; dd < 32; ++dd) o0[dd] *= al0;
        m0 = nm0;

        float p0[4];
#pragma unroll
        for (int i = 0; i < 4; ++i) { p0[i] = fexp(s0[i] - m0); l0 += p0[i]; }

#pragma unroll
        for (int i = 0; i < 4; ++i) {
            const int kk = i * 16 + lane;
#pragma unroll
            for (int dd = 0; dd < 32; dd += 4) {
                const float4 vv = *(const float4*)&Vs[kk][dd];
                o0[dd+0] = fmaf(p0[i], vv.x, o0[dd+0]);
                o0[dd+1] = fmaf(p0[i], vv.y, o0[dd+1]);
                o0[dd+2] = fmaf(p0[i], vv.z, o0[dd+2]);
                o0[dd+3] = fmaf(p0[i], vv.w, o0[dd+3]);
            }
        }
    }

#pragma unroll
    for (int off = 8; off > 0; off >>= 1) {
        l0 += __shfl_down(l0, off, 16);
#pragma unroll
        for (int dd = 0; dd < 32; ++dd) o0[dd] += __shfl_down(o0[dd], off, 16);
    }
    if (lane == 0) {
        const float i0 = 1.f / l0;
        bf16* op0 = o + ((long)(b * L_SEQ + q0) * D_MODEL + hh * DK);
#pragma unroll
        for (int dd = 0; dd < 32; ++dd) op0[dd] = __float2bfloat16(o0[dd] * i0);
    }
}

// ---------------------------------------------------------------------------

extern "C" void kernel_launch(void* const* d_in, const int* in_sizes, int n_in,
                              void* d_out, int out_size, void* d_ws, size_t ws_size,
                              hipStream_t stream) {
    const float* X   = (const float*)d_in[0];
    const float* MEM = (const float*)d_in[1];
    const float* CW  = (const float*)d_in[5];
    const float* CB  = (const float*)d_in[6];
    const float* DTW = (const float*)d_in[8];
    const float* DTB = (const float*)d_in[9];
    const float* ALG = (const float*)d_in[10];
    const float* DP  = (const float*)d_in[11];
    const float* N1A = (const float*)d_in[13];
    const float* N1B = (const float*)d_in[14];
    const float* N2A = (const float*)d_in[15];
    const float* N2B = (const float*)d_in[16];
    const float* N3A = (const float*)d_in[17];
    const float* N3B = (const float*)d_in[18];
    const float* WQB = (const float*)d_in[20];
    const float* WKB = (const float*)d_in[22];
    const float* WVB = (const float*)d_in[24];
    const float* WOB = (const float*)d_in[26];
    const float* W1B = (const float*)d_in[28];
    const float* W2B = (const float*)d_in[30];
    const float* INW = (const float*)d_in[4];
    const float* XPW = (const float*)d_in[7];
    const float* OPW = (const float*)d_in[12];
    const float* WQ  = (const float*)d_in[19];
    const float* WKw = (const float*)d_in[21];
    const float* WVw = (const float*)d_in[23];
    const float* WO  = (const float*)d_in[25];
    const float* W1  = (const float*)d_in[27];
    const float* W2  = (const float*)d_in[29];
    float* out = (float*)d_out;

    // ---- bf16 arena ----
    bf16* bp = (bf16*)d_ws;
    bf16* ub   = bp;  bp += (long)R_TOT * D_INNER;
    bf16* ybb  = bp;  bp += (long)R_TOT * D_INNER;
    bf16* ffab = ybb;
    bf16* xzb  = bp;  bp += (long)R_TOT * 2 * D_INNER;   // bf16 xz
    bf16* ln1b = bp;  bp += (long)R_TOT * D_MODEL;
    bf16* aob  = ln1b;
    bf16* ln2b = bp;  bp += (long)R_TOT * D_MODEL;
    bf16* ln3b = ln2b;
    bf16* arena = bp; bp += S_TOT;
    bf16* MEMb = arena;
    bf16* INWb = MEMb + S_MEM;
    bf16* XPWb = INWb + S_INW;
    bf16* OPWb = XPWb + S_XPW;
    bf16* WQb  = OPWb + S_OPW;
    bf16* WKb  = WQb + S_WQ;
    bf16* WVb  = WKb + S_WK;
    bf16* WOb  = WVb + S_WV;
    bf16* W1b  = WOb + S_WO;
    bf16* W2b  = W1b + S_W1;

    // ---- f32 buffers (h1,qb,kb,vb contiguous for one-shot zeroing) ----
    float* p = (float*)(bp + ((((long)(bp - (bf16*)d_ws)) & 1) ? 1 : 0));
    float* uT  = p;                                  p += (long)R_TOT * D_INNER;
    float* dbl = p;                                  p += (long)R_TOT * DBL_LD;
    float* dtT = p;                                  p += (long)R_TOT * D_INNER;
    float* ysT = p;                                  p += (long)R_TOT * D_INNER;
    float* h1  = p;                                  p += (long)R_TOT * D_MODEL;
    float* qb  = p;                                  p += (long)R_TOT * D_MODEL;
    float* kb  = p;                                  p += (long)R_TOT * D_MODEL;
    float* vb  = p;                                  p += (long)R_TOT * D_MODEL;
    float* h2  = p;                                  p += (long)R_TOT * D_MODEL;

    const dim3 blk256(256);
    const int MT64 = R_TOT / 64;   // 16

    // 0. pack weights + memory to bf16 + ln1 + zero h1/qb/kb/vb/out/dbl
    pack_ln1<<<PACK_BLKS + R_TOT + ZERO_BLKS, blk256, 0, stream>>>(
        MEM, INW, XPW, OPW, WQ, WKw, WVw, WO, W1, W2, arena,
        X, N1A, N1B, ln1b, h1, out, dbl);

    // 1. xz = ln1 @ in_proj^T   [R,2048] -> bf16
    mfma_gemm<0><<<dim3(2 * D_INNER / 64, MT64), blk256, 0, stream>>>(
        ln1b, INWb, D_MODEL, nullptr, xzb, 2 * D_INNER, nullptr, nullptr,
        R_TOT, 2 * D_INNER);

    // 2. conv+silu (bf16 xz) -> ub (bf16) + uT (f32 transposed)
    conv_silu_T<<<dim3(D_INNER / 64, L_SEQ / 64, B_SZ), blk256, 0, stream>>>(
        xzb, CW, CB, ub, uT);

    // 3. x_proj (split-K=4) + k/v (split-K=2, off critical path) merged
    xproj_kv_gemm<<<dim3((DBL_LD + 63) / 64, MT64, 8), blk256, 0, stream>>>(
        ub, XPWb, dbl, MEMb, WKb, WVb, WKB, WVB, kb, vb);

    // 4. dt = softplus(dbl[:,:16] @ dt_proj^T + b) -> dtT directly
    dt_gemm_T<<<dim3(D_INNER / 64, MT64), blk256, 0, stream>>>(dbl, DTW, DTB, dtT);

    // 5. fused segmented scan -> ysT
    scan_fused<<<B_SZ * D_INNER, dim3(1024), 0, stream>>>(dtT, uT, dbl, ALG, ysT);

    // 6. gate (double transpose, bf16 z) -> bf16 y[row][d]
    gate_kernel<<<dim3(D_INNER / 64, L_SEQ / 64, B_SZ), blk256, 0, stream>>>(
        ysT, uT, DP, xzb, ybb);

    // 7. h1 = x + y @ out_proj^T  (split-K=4, 256 blocks, atomic f32)
    splitk_gemm<4><<<dim3(D_MODEL / 64, MT64, 4), blk256, 0, stream>>>(
        ybb, OPWb, D_INNER, h1, D_MODEL, nullptr, X, R_TOT, D_MODEL);

    // 8. ln2 -> bf16
    ln_kernel<<<R_TOT, blk256, 0, stream>>>(h1, N2A, N2B, ln2b);

    // 9. q only (split-K=2, 128 blocks, atomic f32; k/v already done)
    q_gemm<<<dim3(D_MODEL / 64, MT64, 2), blk256, 0, stream>>>(ln2b, WQb, WQB, qb);

    // 10. attention -> bf16 (512 blocks)
    attn_kernel<<<dim3(L_SEQ / QT, N_HEADS, B_SZ), blk256, 0, stream>>>(qb, kb, vb, aob);

    // 11. h2 = h1 + ao @ wo^T + wo_b (f32) + fused LN3 -> bf16 (K=256)
    gemm16_ln<<<R_TOT / 16, blk256, 0, stream>>>(
        aob, WOb, D_MODEL, WOB, h1, h2, N3A, N3B, ln3b);

    // 12. ffa = relu(ln3 @ w1^T + b) -> bf16
    mfma_gemm<1><<<dim3(D_FF / 64, MT64), blk256, 0, stream>>>(
        ln3b, W1b, D_MODEL, nullptr, ffab, D_FF, W1B, nullptr, R_TOT, D_FF);

    // 13. out = h2 + ffa @ w2^T + b  (split-K=4, 256 blocks, atomic f32)
    splitk_gemm<4><<<dim3(D_MODEL / 64, MT64, 4), blk256, 0, stream>>>(
        ffab, W2b, D_FF, out, D_MODEL, W2B, h2, R_TOT, D_MODEL);

    (void)in_sizes; (void)n_in; (void)out_size; (void)ws_size;
}